// Round 12
// baseline (359.483 us; speedup 1.0000x reference)
//
#include <hip/hip_runtime.h>
#include <hip/hip_bf16.h>
#include <hip/hip_fp16.h>

#define IN_CH 128
#define NODES_PER_BUCKET 128
#define BUCKET_CAP 5120     // mean 4096, sigma ~64; 16-sigma headroom
#define EPB 4096            // edges per scatter block (dense 16KB pair segment)

using f32x2 = __attribute__((ext_vector_type(2))) float;

__device__ __forceinline__ float sigmoidf_(float x) { return 1.0f / (1.0f + __expf(-x)); }
__device__ __forceinline__ __half2 u2h(unsigned u) { return __builtin_bit_cast(__half2, u); }
__device__ __forceinline__ unsigned packh2(float a, float b) {
    return __builtin_bit_cast(unsigned, __float22half2_rn(make_float2(a, b)));
}

#if __has_builtin(__builtin_amdgcn_cvt_pk_f32_fp8) && __has_builtin(__builtin_amdgcn_cvt_pk_fp8_f32)
#define FP8_HW 1
#else
#define FP8_HW 0
__device__ __forceinline__ unsigned fp8_enc1(float f) {
    unsigned short us = __builtin_bit_cast(unsigned short, __float2half(f));
    unsigned s = (us >> 8) & 0x80u;
    unsigned mag = us & 0x7fffu;
    if (mag < 0x2400u) return s;            // FTZ
    unsigned t = mag - 0x2000u;             // rebias 15->7
    t += 0x3Fu + ((t >> 7) & 1u);           // RNE
    unsigned r = t >> 7;
    if (r > 0x7Eu) r = 0x7Eu;
    return s | r;
}
__device__ __forceinline__ float fp8_dec1(unsigned v) {
    unsigned s = (v & 0x80u) << 8;
    unsigned m = v & 0x7Fu;
    unsigned h = m ? (((m << 7) + 0x2000u) | s) : s;
    return __half2float(__builtin_bit_cast(__half, (unsigned short)h));
}
#endif

// decode 16 fp8 (uint4) and accumulate into 16 f32
__device__ __forceinline__ void acc16(float* a, uint4 v) {
#if FP8_HW
    f32x2 t;
    t = __builtin_amdgcn_cvt_pk_f32_fp8(v.x, false); a[0] += t[0];  a[1] += t[1];
    t = __builtin_amdgcn_cvt_pk_f32_fp8(v.x, true);  a[2] += t[0];  a[3] += t[1];
    t = __builtin_amdgcn_cvt_pk_f32_fp8(v.y, false); a[4] += t[0];  a[5] += t[1];
    t = __builtin_amdgcn_cvt_pk_f32_fp8(v.y, true);  a[6] += t[0];  a[7] += t[1];
    t = __builtin_amdgcn_cvt_pk_f32_fp8(v.z, false); a[8] += t[0];  a[9] += t[1];
    t = __builtin_amdgcn_cvt_pk_f32_fp8(v.z, true);  a[10] += t[0]; a[11] += t[1];
    t = __builtin_amdgcn_cvt_pk_f32_fp8(v.w, false); a[12] += t[0]; a[13] += t[1];
    t = __builtin_amdgcn_cvt_pk_f32_fp8(v.w, true);  a[14] += t[0]; a[15] += t[1];
#else
    unsigned d[4] = {v.x, v.y, v.z, v.w};
#pragma unroll
    for (int q = 0; q < 4; q++)
#pragma unroll
        for (int b = 0; b < 4; b++) a[q * 4 + b] += fp8_dec1((d[q] >> (8 * b)) & 0xffu);
#endif
}

__device__ __forceinline__ unsigned pack4fp8(float a, float b, float c, float d) {
#if FP8_HW
    unsigned r = 0;
    r = __builtin_amdgcn_cvt_pk_fp8_f32(a, b, r, false);
    r = __builtin_amdgcn_cvt_pk_fp8_f32(c, d, r, true);
    return r;
#else
    return fp8_enc1(a) | (fp8_enc1(b) << 8) | (fp8_enc1(c) << 16) | (fp8_enc1(d) << 24);
#endif
}

// ---------------- CSR build: per-block bucket-sorted segments ----------------
// Each block sorts its EPB edges by bucket into its OWN dense pairBuf segment
// (writes confined to a 16KB window -> full-line eviction, ~13MB total WRITE).
// Publishes per-(block,bucket) exclusive offsets in bbo[blk*NB+b] and adds to
// global bucketCnt totals.
__global__ __launch_bounds__(256) void k_scatter2(const int* __restrict__ src,
                                                  const int* __restrict__ dst, int E,
                                                  int* __restrict__ bucketCnt, int NB,
                                                  unsigned* __restrict__ pairBuf,
                                                  int* __restrict__ bbo) {
    __shared__ int hist[1024];
    __shared__ int part[256];
    int blk = blockIdx.x;
    int tid = threadIdx.x;
    for (int t = tid; t < 1024; t += 256) hist[t] = 0;
    __syncthreads();
    int base = blk * EPB;
    int end = min(base + EPB, E);
    for (int i = base + tid; i < end; i += 256)
        atomicAdd(&hist[dst[i] >> 7], 1);
    __syncthreads();
    // scan 1024 bucket counts (4 per thread) -> block-local exclusive offsets
    int b0 = tid * 4;
    int v[4];
    int s = 0;
#pragma unroll
    for (int j = 0; j < 4; j++) { v[j] = hist[b0 + j]; s += v[j]; }
    part[tid] = s;
    __syncthreads();
    for (int off = 1; off < 256; off <<= 1) {
        int u = (tid >= off) ? part[tid - off] : 0;
        __syncthreads();
        part[tid] += u;
        __syncthreads();
    }
    int run = part[tid] - s;
    size_t bb = (size_t)blk * NB;
#pragma unroll
    for (int j = 0; j < 4; j++) {
        int b = b0 + j;
        if (b < NB) {
            bbo[bb + b] = run;
            if (v[j]) atomicAdd(&bucketCnt[b], v[j]);
        }
        hist[b] = run;  // becomes cursor for pass 2
        run += v[j];
    }
    __syncthreads();
    // pass 2: place pairs into this block's dense segment, bucket-ordered
    unsigned* seg = pairBuf + (size_t)blk * EPB;
    for (int i = base + tid; i < end; i += 256) {
        int d = dst[i];
        int b = d >> 7;
        int pos = atomicAdd(&hist[b], 1);
        seg[pos] = ((unsigned)src[i] << 7) | (unsigned)(d & 127);
    }
}

// single-block exclusive scan of per-bucket totals -> bucketBase; rowptr[n]=total
__global__ __launch_bounds__(1024) void k_scan_buckets(const int* __restrict__ bucketCnt, int NB,
                                                       int* __restrict__ bucketBase,
                                                       int* __restrict__ rowptr, int n) {
    __shared__ int sh[1024];
    int t = threadIdx.x;
    int v = (t < NB) ? min(bucketCnt[t], BUCKET_CAP) : 0;
    sh[t] = v;
    __syncthreads();
    for (int off = 1; off < 1024; off <<= 1) {
        int u = (t >= off) ? sh[t - off] : 0;
        __syncthreads();
        sh[t] += u;
        __syncthreads();
    }
    if (t < NB) bucketBase[t] = sh[t] - v;
    if (t == 1023) rowptr[n] = sh[1023];
}

// fused: per-bucket node hist -> LDS scan -> rowptr/dinv -> place col.
// One block per bucket; iterates the per-block runs via bbo offsets (16-lane groups).
__global__ __launch_bounds__(256) void k_place2(const unsigned* __restrict__ pairBuf,
                                                const int* __restrict__ bbo,
                                                const int* __restrict__ bucketCnt,
                                                const int* __restrict__ bucketBase,
                                                int* __restrict__ rowptr,
                                                float* __restrict__ dinv,
                                                int* __restrict__ col,
                                                int n, int NB, int nblk, int E) {
    __shared__ int hist[NODES_PER_BUCKET];
    __shared__ int excl[NODES_PER_BUCKET];
    __shared__ int stage[BUCKET_CAP];
    int b = blockIdx.x;
    int tid = threadIdx.x;
    int first = b * NODES_PER_BUCKET;
    if (tid < NODES_PER_BUCKET) hist[tid] = 0;
    __syncthreads();
    int gg = tid >> 4;   // 16 groups of 16 lanes
    int gl = tid & 15;
    // pass 1: per-node histogram over all block-runs of this bucket
    for (int blk = gg; blk < nblk; blk += 16) {
        int off0 = bbo[(size_t)blk * NB + b];
        int off1 = (b + 1 < NB) ? bbo[(size_t)blk * NB + b + 1] : min(EPB, E - blk * EPB);
        const unsigned* pp = pairBuf + (size_t)blk * EPB;
        for (int e = off0 + gl; e < off1; e += 16)
            atomicAdd(&hist[pp[e] & 127], 1);
    }
    __syncthreads();
    int v = (tid < NODES_PER_BUCKET) ? hist[tid] : 0;
    if (tid < NODES_PER_BUCKET) excl[tid] = v;
    __syncthreads();
    for (int off = 1; off < NODES_PER_BUCKET; off <<= 1) {
        int u = (tid < NODES_PER_BUCKET && tid >= off) ? excl[tid - off] : 0;
        __syncthreads();
        if (tid < NODES_PER_BUCKET) excl[tid] += u;
        __syncthreads();
    }
    int base = bucketBase[b];
    if (tid < NODES_PER_BUCKET) {
        int node = first + tid;
        int ex = excl[tid] - v;
        if (node < n) {
            rowptr[node] = base + ex;
            dinv[node] = rsqrtf((float)(v + 1));  // +1 self loop
        }
        hist[tid] = ex;  // reuse as cursor
    }
    __syncthreads();
    // pass 2: place into stage (node-ordered), then contiguous col flush
    for (int blk = gg; blk < nblk; blk += 16) {
        int off0 = bbo[(size_t)blk * NB + b];
        int off1 = (b + 1 < NB) ? bbo[(size_t)blk * NB + b + 1] : min(EPB, E - blk * EPB);
        const unsigned* pp = pairBuf + (size_t)blk * EPB;
        for (int e = off0 + gl; e < off1; e += 16) {
            unsigned pr = pp[e];
            int lpos = atomicAdd(&hist[pr & 127], 1);
            if (lpos < BUCKET_CAP) stage[lpos] = (int)(pr >> 7);
        }
    }
    __syncthreads();
    int cb = min(bucketCnt[b], BUCKET_CAP);
    for (int i = tid; i < cb; i += 256) col[base + i] = stage[i];
}

// ---------------- GEMM: Y = (X @ W) * dinv[row], output fp8(e4m3) ----------------
template <int OUTC, bool INHALF>
__global__ __launch_bounds__(256) void k_gemm_scale(const void* __restrict__ Xv,
                                                    const float* __restrict__ W,
                                                    const float* __restrict__ dinv,
                                                    unsigned char* __restrict__ Yb, int n) {
    constexpr int TN = OUTC / 16;  // 8 (128) or 4 (64)
    __shared__ float xs[16][65];
    __shared__ float ws[16 * OUTC];
    int tid = threadIdx.x;
    int row0 = blockIdx.x * 64;
    int tx = tid & 15;
    int ty = tid >> 4;

    float acc[4][TN];
#pragma unroll
    for (int i = 0; i < 4; i++)
#pragma unroll
        for (int j = 0; j < TN; j++) acc[i][j] = 0.0f;

    for (int k0 = 0; k0 < IN_CH; k0 += 16) {
        {
            int r = tid >> 2;
            int kq = (tid & 3) * 4;
            int grow = row0 + r;
            float4 xv = make_float4(0.f, 0.f, 0.f, 0.f);
            if (grow < n) {
                if constexpr (INHALF) {
                    uint2 xu = *(const uint2*)((const unsigned short*)Xv + (size_t)grow * IN_CH + k0 + kq);
                    __half2 p0 = u2h(xu.x), p1 = u2h(xu.y);
                    xv = make_float4(__low2float(p0), __high2float(p0), __low2float(p1), __high2float(p1));
                } else {
                    xv = *(const float4*)((const float*)Xv + (size_t)grow * IN_CH + k0 + kq);
                }
            }
            xs[kq + 0][r] = xv.x;
            xs[kq + 1][r] = xv.y;
            xs[kq + 2][r] = xv.z;
            xs[kq + 3][r] = xv.w;
        }
        {
            const float4* wsrc = (const float4*)(W + k0 * OUTC);
            float4* wdst = (float4*)ws;
#pragma unroll
            for (int j = 0; j < OUTC / 64; j++) wdst[tid + j * 256] = wsrc[tid + j * 256];
        }
        __syncthreads();
#pragma unroll
        for (int kk = 0; kk < 16; kk++) {
            float a[4];
            *(float4*)a = *(const float4*)&xs[kk][ty * 4];
            float bb[TN];
#pragma unroll
            for (int j = 0; j < TN / 4; j++)
                *(float4*)&bb[j * 4] = *(const float4*)&ws[kk * OUTC + tx * TN + j * 4];
#pragma unroll
            for (int i = 0; i < 4; i++)
#pragma unroll
                for (int j = 0; j < TN; j++) acc[i][j] = fmaf(a[i], bb[j], acc[i][j]);
        }
        __syncthreads();
    }
#pragma unroll
    for (int i = 0; i < 4; i++) {
        int grow = row0 + ty * 4 + i;
        if (grow < n) {
            float dvv = dinv[grow];
            if constexpr (TN == 8) {
                uint2 o;
                o.x = pack4fp8(acc[i][0] * dvv, acc[i][1] * dvv, acc[i][2] * dvv, acc[i][3] * dvv);
                o.y = pack4fp8(acc[i][4] * dvv, acc[i][5] * dvv, acc[i][6] * dvv, acc[i][7] * dvv);
                ((uint2*)(Yb + (size_t)grow * 128))[tx] = o;
            } else {
                unsigned o = pack4fp8(acc[i][0] * dvv, acc[i][1] * dvv, acc[i][2] * dvv, acc[i][3] * dvv);
                ((unsigned*)(Yb + (size_t)grow * 64))[tx] = o;
            }
        }
    }
}

// ---------------- aggregation: out = act(dinv[d]*(sum y[s] + y[d]) + b) ----------------
// FOUR NODES PER WAVE: 16-lane quarter q serves node wid*4+q. Within a quarter:
// LPE=C/16 lanes per row (16B/lane), EPI=16/LPE edges per gather instr.
template <int C, bool OUTHALF>
__global__ __launch_bounds__(256) void k_agg(const uint4* __restrict__ Y4,
                                             const int* __restrict__ rowptr,
                                             const int* __restrict__ col,
                                             const float* __restrict__ dinv,
                                             const float* __restrict__ bias,
                                             void* __restrict__ out, int n, int zidx) {
    constexpr int LPE = C / 16;     // lanes per row: 8 (C=128) or 4 (C=64)
    constexpr int EPI = 16 / LPE;   // edges per gather instr per quarter: 2 or 4
    constexpr int RS = C / 16;      // uint4 per row
    int gid = blockIdx.x * blockDim.x + threadIdx.x;
    int wid = gid >> 6;
    int lane = gid & 63;
    int node = wid * 4 + (lane >> 4);
    if (node >= n) return;
    int hl = lane & 15;
    int g = hl / LPE;
    int sub = hl % LPE;
    int s0 = rowptr[node], s1 = rowptr[node + 1];

    float a0[16], a1[16];
#pragma unroll
    for (int k = 0; k < 16; k++) { a0[k] = 0.f; a1[k] = 0.f; }

    // self loop: group 0 of each quarter real, others hit zero row
    {
        int idx = (g == 0) ? node : zidx;
        uint4 v = Y4[(size_t)idx * RS + sub];
        acc16(a0, v);
    }
    int i = s0;
    for (; i + 2 * EPI <= s1; i += 2 * EPI) {
        int ca = col[i + g];
        int cb = col[i + EPI + g];
        uint4 va = Y4[(size_t)ca * RS + sub];
        uint4 vb = Y4[(size_t)cb * RS + sub];
        acc16(a0, va);
        acc16(a1, vb);
    }
    for (; i < s1; i += EPI) {
        int e = i + g;
        int c = col[min(e, s1 - 1)];
        int idx = (e < s1) ? c : zidx;
        uint4 v = Y4[(size_t)idx * RS + sub];
        acc16(a0, v);
    }
#pragma unroll
    for (int k = 0; k < 16; k++) a0[k] += a1[k];
    // reduce within the 16-lane quarter (xor masks < 16 stay in-quarter)
#pragma unroll
    for (int m = LPE; m < 16; m <<= 1) {
#pragma unroll
        for (int k = 0; k < 16; k++) a0[k] += __shfl_xor(a0[k], m, 64);
    }
    if (hl < LPE) {
        float dv = dinv[node];
        float4 bv[4];
        bv[0] = *(const float4*)&bias[sub * 16];
        bv[1] = *(const float4*)&bias[sub * 16 + 4];
        bv[2] = *(const float4*)&bias[sub * 16 + 8];
        bv[3] = *(const float4*)&bias[sub * 16 + 12];
        float o[16];
#pragma unroll
        for (int q = 0; q < 4; q++) {
            const float* bq = (const float*)&bv[q];
#pragma unroll
            for (int b = 0; b < 4; b++) o[q * 4 + b] = sigmoidf_(a0[q * 4 + b] * dv + bq[b]);
        }
        if constexpr (OUTHALF) {
            constexpr int OR = C / 8;  // uint4 per f16 row
            uint4 h0, h1;
            h0.x = packh2(o[0], o[1]);   h0.y = packh2(o[2], o[3]);
            h0.z = packh2(o[4], o[5]);   h0.w = packh2(o[6], o[7]);
            h1.x = packh2(o[8], o[9]);   h1.y = packh2(o[10], o[11]);
            h1.z = packh2(o[12], o[13]); h1.w = packh2(o[14], o[15]);
            ((uint4*)out)[(size_t)node * OR + sub * 2] = h0;
            ((uint4*)out)[(size_t)node * OR + sub * 2 + 1] = h1;
        } else {
            float* op = (float*)out + (size_t)node * C + sub * 16;
            *(float4*)(op + 0)  = make_float4(o[0], o[1], o[2], o[3]);
            *(float4*)(op + 4)  = make_float4(o[4], o[5], o[6], o[7]);
            *(float4*)(op + 8)  = make_float4(o[8], o[9], o[10], o[11]);
            *(float4*)(op + 12) = make_float4(o[12], o[13], o[14], o[15]);
        }
    }
}

extern "C" void kernel_launch(void* const* d_in, const int* in_sizes, int n_in,
                              void* d_out, int out_size, void* d_ws, size_t ws_size,
                              hipStream_t stream) {
    const float* x  = (const float*)d_in[0];
    const int* eidx = (const int*)d_in[1];
    const float* W1 = (const float*)d_in[2];
    const float* b1 = (const float*)d_in[3];
    const float* W2 = (const float*)d_in[4];
    const float* b2 = (const float*)d_in[5];
    float* out = (float*)d_out;

    int n = in_sizes[0] / IN_CH;
    int E = in_sizes[1] / 2;
    const int* srcv = eidx;
    const int* dstv = eidx + E;
    int NB = (n + NODES_PER_BUCKET - 1) / NODES_PER_BUCKET;  // 782 (must be <=1024)
    int nblk = (E + EPB - 1) / EPB;                          // 782 scatter blocks

    char* w = (char*)d_ws;
    auto alloc = [&](size_t bytes) {
        char* p = w;
        w += (bytes + 255) & ~(size_t)255;
        return p;
    };
    int* bucketCnt      = (int*)alloc((size_t)NB * 4);
    int* bucketBase     = (int*)alloc((size_t)NB * 4);
    unsigned* pairBuf   = (unsigned*)alloc((size_t)nblk * EPB * 4);    // per-block dense segments
    int* bbo            = (int*)alloc((size_t)nblk * NB * 4);          // per-(block,bucket) offsets
    int* rowptr         = (int*)alloc(((size_t)n + 1) * 4);
    float* dinv         = (float*)alloc((size_t)n * 4);
    int* col            = (int*)alloc((size_t)E * 4);
    unsigned char* y    = (unsigned char*)alloc(((size_t)n + 1) * 128);  // fp8 [n+1][128B]; reused for y2 [n][64B]
    unsigned short* h   = (unsigned short*)alloc((size_t)n * IN_CH * 2); // f16 [n][128]

    hipMemsetAsync(bucketCnt, 0, (size_t)NB * 4, stream);
    // zero row: serves agg1 (row n, 128B rows) and agg2 (row 2n, 64B rows — same bytes)
    hipMemsetAsync(y + (size_t)n * 128, 0, 128, stream);

    k_scatter2<<<nblk, 256, 0, stream>>>(srcv, dstv, E, bucketCnt, NB, pairBuf, bbo);
    k_scan_buckets<<<1, 1024, 0, stream>>>(bucketCnt, NB, bucketBase, rowptr, n);
    k_place2<<<NB, 256, 0, stream>>>(pairBuf, bbo, bucketCnt, bucketBase, rowptr, dinv, col,
                                     n, NB, nblk, E);

    int gemmGrid = (n + 63) / 64;
    int aggGrid = (n + 15) / 16;  // 4 nodes/wave, 4 waves/block

    // layer 1
    k_gemm_scale<128, false><<<gemmGrid, 256, 0, stream>>>(x, W1, dinv, y, n);
    k_agg<128, true><<<aggGrid, 256, 0, stream>>>((const uint4*)y, rowptr, col, dinv, b1, h, n, n);
    // layer 2 (y buffer reused for y2 fp8 [n][64B]; zero row at index 2n = same bytes)
    k_gemm_scale<64, true><<<gemmGrid, 256, 0, stream>>>(h, W2, dinv, y, n);
    k_agg<64, false><<<aggGrid, 256, 0, stream>>>((const uint4*)y, rowptr, col, dinv, b2, out, n, 2 * n);
}

// Round 13
// 279.235 us; speedup vs baseline: 1.2874x; 1.2874x over previous
//
#include <hip/hip_runtime.h>
#include <hip/hip_bf16.h>
#include <hip/hip_fp16.h>

#define IN_CH 128
#define NODES_PER_BUCKET 128
#define BUCKET_CAP 5120     // mean 4096, sigma ~64; 16-sigma headroom
#define EPB 8192            // edges per scatter block (R9 optimum: 391 blocks)

using f32x2 = __attribute__((ext_vector_type(2))) float;

__device__ __forceinline__ float sigmoidf_(float x) { return 1.0f / (1.0f + __expf(-x)); }
__device__ __forceinline__ __half2 u2h(unsigned u) { return __builtin_bit_cast(__half2, u); }
__device__ __forceinline__ unsigned packh2(float a, float b) {
    return __builtin_bit_cast(unsigned, __float22half2_rn(make_float2(a, b)));
}

#if __has_builtin(__builtin_amdgcn_cvt_pk_f32_fp8) && __has_builtin(__builtin_amdgcn_cvt_pk_fp8_f32)
#define FP8_HW 1
#else
#define FP8_HW 0
__device__ __forceinline__ unsigned fp8_enc1(float f) {
    unsigned short us = __builtin_bit_cast(unsigned short, __float2half(f));
    unsigned s = (us >> 8) & 0x80u;
    unsigned mag = us & 0x7fffu;
    if (mag < 0x2400u) return s;            // FTZ
    unsigned t = mag - 0x2000u;             // rebias 15->7
    t += 0x3Fu + ((t >> 7) & 1u);           // RNE
    unsigned r = t >> 7;
    if (r > 0x7Eu) r = 0x7Eu;
    return s | r;
}
__device__ __forceinline__ float fp8_dec1(unsigned v) {
    unsigned s = (v & 0x80u) << 8;
    unsigned m = v & 0x7Fu;
    unsigned h = m ? (((m << 7) + 0x2000u) | s) : s;
    return __half2float(__builtin_bit_cast(__half, (unsigned short)h));
}
#endif

// decode 16 fp8 (uint4) and accumulate into 16 f32
__device__ __forceinline__ void acc16(float* a, uint4 v) {
#if FP8_HW
    f32x2 t;
    t = __builtin_amdgcn_cvt_pk_f32_fp8(v.x, false); a[0] += t[0];  a[1] += t[1];
    t = __builtin_amdgcn_cvt_pk_f32_fp8(v.x, true);  a[2] += t[0];  a[3] += t[1];
    t = __builtin_amdgcn_cvt_pk_f32_fp8(v.y, false); a[4] += t[0];  a[5] += t[1];
    t = __builtin_amdgcn_cvt_pk_f32_fp8(v.y, true);  a[6] += t[0];  a[7] += t[1];
    t = __builtin_amdgcn_cvt_pk_f32_fp8(v.z, false); a[8] += t[0];  a[9] += t[1];
    t = __builtin_amdgcn_cvt_pk_f32_fp8(v.z, true);  a[10] += t[0]; a[11] += t[1];
    t = __builtin_amdgcn_cvt_pk_f32_fp8(v.w, false); a[12] += t[0]; a[13] += t[1];
    t = __builtin_amdgcn_cvt_pk_f32_fp8(v.w, true);  a[14] += t[0]; a[15] += t[1];
#else
    unsigned d[4] = {v.x, v.y, v.z, v.w};
#pragma unroll
    for (int q = 0; q < 4; q++)
#pragma unroll
        for (int b = 0; b < 4; b++) a[q * 4 + b] += fp8_dec1((d[q] >> (8 * b)) & 0xffu);
#endif
}

__device__ __forceinline__ unsigned pack4fp8(float a, float b, float c, float d) {
#if FP8_HW
    unsigned r = 0;
    r = __builtin_amdgcn_cvt_pk_fp8_f32(a, b, r, false);
    r = __builtin_amdgcn_cvt_pk_fp8_f32(c, d, r, true);
    return r;
#else
    return fp8_enc1(a) | (fp8_enc1(b) << 8) | (fp8_enc1(c) << 16) | (fp8_enc1(d) << 24);
#endif
}

// ---------------- bucketed CSR build (R9 structure + int4 loads) ----------------
__global__ __launch_bounds__(256) void k_bucket_scatter(const int* __restrict__ src,
                                                        const int* __restrict__ dst, int E,
                                                        int* __restrict__ bucketCnt, int NB,
                                                        unsigned* __restrict__ pairBuf) {
    __shared__ int hist[1024];
    int tid = threadIdx.x;
    for (int t = tid; t < 1024; t += 256) hist[t] = 0;
    __syncthreads();
    int base = blockIdx.x * EPB;
    int end = min(base + EPB, E);
    int cnt4 = (end - base) >> 2;
    const int4* d4 = (const int4*)(dst + base);
    const int4* s4 = (const int4*)(src + base);
    // pass 1: bucket histogram (4 edges per VMEM)
    for (int i = tid; i < cnt4; i += 256) {
        int4 d = d4[i];
        atomicAdd(&hist[d.x >> 7], 1);
        atomicAdd(&hist[d.y >> 7], 1);
        atomicAdd(&hist[d.z >> 7], 1);
        atomicAdd(&hist[d.w >> 7], 1);
    }
    for (int i = base + (cnt4 << 2) + tid; i < end; i += 256)
        atomicAdd(&hist[dst[i] >> 7], 1);
    __syncthreads();
    // reserve global ranges; hist becomes running cursor
    for (int t = tid; t < NB; t += 256) {
        int c = hist[t];
        hist[t] = c ? atomicAdd(&bucketCnt[t], c) : 0;
    }
    __syncthreads();
    // pass 2: place pairs (4 edges per VMEM pair)
    for (int i = tid; i < cnt4; i += 256) {
        int4 d = d4[i];
        int4 s = s4[i];
        int b, p;
        b = d.x >> 7; p = atomicAdd(&hist[b], 1);
        if (p < BUCKET_CAP) pairBuf[(size_t)b * BUCKET_CAP + p] = ((unsigned)s.x << 7) | (unsigned)(d.x & 127);
        b = d.y >> 7; p = atomicAdd(&hist[b], 1);
        if (p < BUCKET_CAP) pairBuf[(size_t)b * BUCKET_CAP + p] = ((unsigned)s.y << 7) | (unsigned)(d.y & 127);
        b = d.z >> 7; p = atomicAdd(&hist[b], 1);
        if (p < BUCKET_CAP) pairBuf[(size_t)b * BUCKET_CAP + p] = ((unsigned)s.z << 7) | (unsigned)(d.z & 127);
        b = d.w >> 7; p = atomicAdd(&hist[b], 1);
        if (p < BUCKET_CAP) pairBuf[(size_t)b * BUCKET_CAP + p] = ((unsigned)s.w << 7) | (unsigned)(d.w & 127);
    }
    for (int i = base + (cnt4 << 2) + tid; i < end; i += 256) {
        int d = dst[i];
        int b = d >> 7;
        int p = atomicAdd(&hist[b], 1);
        if (p < BUCKET_CAP) pairBuf[(size_t)b * BUCKET_CAP + p] = ((unsigned)src[i] << 7) | (unsigned)(d & 127);
    }
}

// single-block exclusive scan of per-bucket totals -> bucketBase; rowptr[n]=total
__global__ __launch_bounds__(1024) void k_scan_buckets(const int* __restrict__ bucketCnt, int NB,
                                                       int* __restrict__ bucketBase,
                                                       int* __restrict__ rowptr, int n) {
    __shared__ int sh[1024];
    int t = threadIdx.x;
    int v = (t < NB) ? min(bucketCnt[t], BUCKET_CAP) : 0;
    sh[t] = v;
    __syncthreads();
    for (int off = 1; off < 1024; off <<= 1) {
        int u = (t >= off) ? sh[t - off] : 0;
        __syncthreads();
        sh[t] += u;
        __syncthreads();
    }
    if (t < NB) bucketBase[t] = sh[t] - v;
    if (t == 1023) rowptr[n] = sh[1023];
}

// fused: per-bucket node hist -> LDS scan -> rowptr/dinv -> place col. One block per bucket.
__global__ __launch_bounds__(256) void k_bucket_place2(const unsigned* __restrict__ pairBuf,
                                                       const int* __restrict__ bucketCnt,
                                                       const int* __restrict__ bucketBase,
                                                       int* __restrict__ rowptr,
                                                       float* __restrict__ dinv,
                                                       int* __restrict__ col, int n) {
    __shared__ int hist[NODES_PER_BUCKET];
    __shared__ int excl[NODES_PER_BUCKET];
    __shared__ int stage[BUCKET_CAP];
    int b = blockIdx.x;
    int tid = threadIdx.x;
    int first = b * NODES_PER_BUCKET;
    if (tid < NODES_PER_BUCKET) hist[tid] = 0;
    __syncthreads();
    int cb = min(bucketCnt[b], BUCKET_CAP);
    const unsigned* p = pairBuf + (size_t)b * BUCKET_CAP;
    for (int e = tid; e < cb; e += 256) atomicAdd(&hist[p[e] & 127], 1);
    __syncthreads();
    int v = (tid < NODES_PER_BUCKET) ? hist[tid] : 0;
    if (tid < NODES_PER_BUCKET) excl[tid] = v;
    __syncthreads();
    for (int off = 1; off < NODES_PER_BUCKET; off <<= 1) {
        int u = (tid < NODES_PER_BUCKET && tid >= off) ? excl[tid - off] : 0;
        __syncthreads();
        if (tid < NODES_PER_BUCKET) excl[tid] += u;
        __syncthreads();
    }
    int base = bucketBase[b];
    if (tid < NODES_PER_BUCKET) {
        int node = first + tid;
        int ex = excl[tid] - v;
        if (node < n) {
            rowptr[node] = base + ex;
            dinv[node] = rsqrtf((float)(v + 1));  // +1 self loop
        }
        hist[tid] = ex;  // reuse as cursor
    }
    __syncthreads();
    for (int e = tid; e < cb; e += 256) {
        unsigned pr = p[e];
        int lpos = atomicAdd(&hist[pr & 127], 1);
        stage[lpos] = (int)(pr >> 7);
    }
    __syncthreads();
    for (int i = tid; i < cb; i += 256) col[base + i] = stage[i];
}

// ---------------- GEMM: Y = (X @ W) * dinv[row], output fp8(e4m3) ----------------
template <int OUTC, bool INHALF>
__global__ __launch_bounds__(256) void k_gemm_scale(const void* __restrict__ Xv,
                                                    const float* __restrict__ W,
                                                    const float* __restrict__ dinv,
                                                    unsigned char* __restrict__ Yb, int n) {
    constexpr int TN = OUTC / 16;  // 8 (128) or 4 (64)
    __shared__ float xs[16][65];
    __shared__ float ws[16 * OUTC];
    int tid = threadIdx.x;
    int row0 = blockIdx.x * 64;
    int tx = tid & 15;
    int ty = tid >> 4;

    float acc[4][TN];
#pragma unroll
    for (int i = 0; i < 4; i++)
#pragma unroll
        for (int j = 0; j < TN; j++) acc[i][j] = 0.0f;

    for (int k0 = 0; k0 < IN_CH; k0 += 16) {
        {
            int r = tid >> 2;
            int kq = (tid & 3) * 4;
            int grow = row0 + r;
            float4 xv = make_float4(0.f, 0.f, 0.f, 0.f);
            if (grow < n) {
                if constexpr (INHALF) {
                    uint2 xu = *(const uint2*)((const unsigned short*)Xv + (size_t)grow * IN_CH + k0 + kq);
                    __half2 p0 = u2h(xu.x), p1 = u2h(xu.y);
                    xv = make_float4(__low2float(p0), __high2float(p0), __low2float(p1), __high2float(p1));
                } else {
                    xv = *(const float4*)((const float*)Xv + (size_t)grow * IN_CH + k0 + kq);
                }
            }
            xs[kq + 0][r] = xv.x;
            xs[kq + 1][r] = xv.y;
            xs[kq + 2][r] = xv.z;
            xs[kq + 3][r] = xv.w;
        }
        {
            const float4* wsrc = (const float4*)(W + k0 * OUTC);
            float4* wdst = (float4*)ws;
#pragma unroll
            for (int j = 0; j < OUTC / 64; j++) wdst[tid + j * 256] = wsrc[tid + j * 256];
        }
        __syncthreads();
#pragma unroll
        for (int kk = 0; kk < 16; kk++) {
            float a[4];
            *(float4*)a = *(const float4*)&xs[kk][ty * 4];
            float bb[TN];
#pragma unroll
            for (int j = 0; j < TN / 4; j++)
                *(float4*)&bb[j * 4] = *(const float4*)&ws[kk * OUTC + tx * TN + j * 4];
#pragma unroll
            for (int i = 0; i < 4; i++)
#pragma unroll
                for (int j = 0; j < TN; j++) acc[i][j] = fmaf(a[i], bb[j], acc[i][j]);
        }
        __syncthreads();
    }
#pragma unroll
    for (int i = 0; i < 4; i++) {
        int grow = row0 + ty * 4 + i;
        if (grow < n) {
            float dvv = dinv[grow];
            if constexpr (TN == 8) {
                uint2 o;
                o.x = pack4fp8(acc[i][0] * dvv, acc[i][1] * dvv, acc[i][2] * dvv, acc[i][3] * dvv);
                o.y = pack4fp8(acc[i][4] * dvv, acc[i][5] * dvv, acc[i][6] * dvv, acc[i][7] * dvv);
                ((uint2*)(Yb + (size_t)grow * 128))[tx] = o;
            } else {
                unsigned o = pack4fp8(acc[i][0] * dvv, acc[i][1] * dvv, acc[i][2] * dvv, acc[i][3] * dvv);
                ((unsigned*)(Yb + (size_t)grow * 64))[tx] = o;
            }
        }
    }
}

// ---------------- aggregation: out = act(dinv[d]*(sum y[s] + y[d]) + b) ----------------
// ONE NODE PER LANE-GROUP (R13): LPE=C/16 lanes own one node's full row (16B/lane);
// NPW=64/LPE nodes per wave (8 for C=128, 16 for C=64). Each lane accumulates its
// own 16 fixed channels -> NO cross-lane reduce at all; self-loop is an all-lane
// gather of the own row. s0/s1 are uniform within a group so loops are group-uniform.
template <int C, bool OUTHALF>
__global__ __launch_bounds__(256) void k_agg(const uint4* __restrict__ Y4,
                                             const int* __restrict__ rowptr,
                                             const int* __restrict__ col,
                                             const float* __restrict__ dinv,
                                             const float* __restrict__ bias,
                                             void* __restrict__ out, int n, int zidx) {
    constexpr int LPE = C / 16;     // lanes per row: 8 (C=128) or 4 (C=64)
    constexpr int NPW = 64 / LPE;   // nodes per wave: 8 or 16
    constexpr int RS = C / 16;      // uint4 per row
    int gid = blockIdx.x * blockDim.x + threadIdx.x;
    int wid = gid >> 6;
    int lane = gid & 63;
    int g = lane / LPE;
    int sub = lane % LPE;
    int node = wid * NPW + g;
    bool valid = node < n;
    int nc = valid ? node : 0;
    int s0 = rowptr[nc];
    int s1 = valid ? rowptr[nc + 1] : s0;

    float a0[16], a1[16];
#pragma unroll
    for (int k = 0; k < 16; k++) { a0[k] = 0.f; a1[k] = 0.f; }

    // self loop: every group gathers its own node's row
    {
        int idx = valid ? node : zidx;
        uint4 v = Y4[(size_t)idx * RS + sub];
        acc16(a0, v);
    }
    int e = s0;
    for (; e + 2 <= s1; e += 2) {
        int ca = col[e];
        int cb = col[e + 1];
        uint4 va = Y4[(size_t)ca * RS + sub];
        uint4 vb = Y4[(size_t)cb * RS + sub];
        acc16(a0, va);
        acc16(a1, vb);
    }
    if (e < s1) {
        uint4 v = Y4[(size_t)col[e] * RS + sub];
        acc16(a0, v);
    }
#pragma unroll
    for (int k = 0; k < 16; k++) a0[k] += a1[k];

    if (valid) {
        float dv = dinv[node];
        float4 bv[4];
        bv[0] = *(const float4*)&bias[sub * 16];
        bv[1] = *(const float4*)&bias[sub * 16 + 4];
        bv[2] = *(const float4*)&bias[sub * 16 + 8];
        bv[3] = *(const float4*)&bias[sub * 16 + 12];
        float o[16];
#pragma unroll
        for (int q = 0; q < 4; q++) {
            const float* bq = (const float*)&bv[q];
#pragma unroll
            for (int b = 0; b < 4; b++) o[q * 4 + b] = sigmoidf_(a0[q * 4 + b] * dv + bq[b]);
        }
        if constexpr (OUTHALF) {
            constexpr int OR = C / 8;  // uint4 per f16 row
            uint4 h0, h1;
            h0.x = packh2(o[0], o[1]);   h0.y = packh2(o[2], o[3]);
            h0.z = packh2(o[4], o[5]);   h0.w = packh2(o[6], o[7]);
            h1.x = packh2(o[8], o[9]);   h1.y = packh2(o[10], o[11]);
            h1.z = packh2(o[12], o[13]); h1.w = packh2(o[14], o[15]);
            ((uint4*)out)[(size_t)node * OR + sub * 2] = h0;
            ((uint4*)out)[(size_t)node * OR + sub * 2 + 1] = h1;
        } else {
            float* op = (float*)out + (size_t)node * C + sub * 16;
            *(float4*)(op + 0)  = make_float4(o[0], o[1], o[2], o[3]);
            *(float4*)(op + 4)  = make_float4(o[4], o[5], o[6], o[7]);
            *(float4*)(op + 8)  = make_float4(o[8], o[9], o[10], o[11]);
            *(float4*)(op + 12) = make_float4(o[12], o[13], o[14], o[15]);
        }
    }
}

extern "C" void kernel_launch(void* const* d_in, const int* in_sizes, int n_in,
                              void* d_out, int out_size, void* d_ws, size_t ws_size,
                              hipStream_t stream) {
    const float* x  = (const float*)d_in[0];
    const int* eidx = (const int*)d_in[1];
    const float* W1 = (const float*)d_in[2];
    const float* b1 = (const float*)d_in[3];
    const float* W2 = (const float*)d_in[4];
    const float* b2 = (const float*)d_in[5];
    float* out = (float*)d_out;

    int n = in_sizes[0] / IN_CH;
    int E = in_sizes[1] / 2;
    const int* srcv = eidx;
    const int* dstv = eidx + E;
    int NB = (n + NODES_PER_BUCKET - 1) / NODES_PER_BUCKET;  // 782 (must be <=1024)

    char* w = (char*)d_ws;
    auto alloc = [&](size_t bytes) {
        char* p = w;
        w += (bytes + 255) & ~(size_t)255;
        return p;
    };
    int* bucketCnt      = (int*)alloc((size_t)NB * 4);
    int* bucketBase     = (int*)alloc((size_t)NB * 4);
    unsigned* pairBuf   = (unsigned*)alloc((size_t)NB * BUCKET_CAP * 4);
    int* rowptr         = (int*)alloc(((size_t)n + 1) * 4);
    float* dinv         = (float*)alloc((size_t)n * 4);
    int* col            = (int*)alloc((size_t)E * 4);
    unsigned char* y    = (unsigned char*)alloc(((size_t)n + 1) * 128);  // fp8 [n+1][128B]; reused for y2 [n][64B]
    unsigned short* h   = (unsigned short*)alloc((size_t)n * IN_CH * 2); // f16 [n][128]

    hipMemsetAsync(bucketCnt, 0, (size_t)NB * 4, stream);
    // zero row: serves agg1 (row n, 128B rows) and agg2 (row 2n, 64B rows — same bytes)
    hipMemsetAsync(y + (size_t)n * 128, 0, 128, stream);

    int nblk = (E + EPB - 1) / EPB;  // 391
    k_bucket_scatter<<<nblk, 256, 0, stream>>>(srcv, dstv, E, bucketCnt, NB, pairBuf);
    k_scan_buckets<<<1, 1024, 0, stream>>>(bucketCnt, NB, bucketBase, rowptr, n);
    k_bucket_place2<<<NB, 256, 0, stream>>>(pairBuf, bucketCnt, bucketBase, rowptr, dinv, col, n);

    int gemmGrid = (n + 63) / 64;

    // layer 1 (8 nodes/wave, 4 waves/block -> 32 nodes/block)
    k_gemm_scale<128, false><<<gemmGrid, 256, 0, stream>>>(x, W1, dinv, y, n);
    k_agg<128, true><<<(n + 31) / 32, 256, 0, stream>>>((const uint4*)y, rowptr, col, dinv, b1, h, n, n);
    // layer 2 (16 nodes/wave -> 64 nodes/block; y reused as fp8 [n][64B], zero row at 2n)
    k_gemm_scale<64, true><<<gemmGrid, 256, 0, stream>>>(h, W2, dinv, y, n);
    k_agg<64, false><<<(n + 63) / 64, 256, 0, stream>>>((const uint4*)y, rowptr, col, dinv, b2, out, n, 2 * n);
}

// Round 14
// 259.725 us; speedup vs baseline: 1.3841x; 1.0751x over previous
//
#include <hip/hip_runtime.h>
#include <hip/hip_bf16.h>
#include <hip/hip_fp16.h>

#define IN_CH 128
#define NODES_PER_BUCKET 128
#define BUCKET_CAP 5120     // mean 4096, sigma ~64; 16-sigma headroom
#define EPB 8192            // edges per scatter block (R9 optimum: 391 blocks)

using f32x2 = __attribute__((ext_vector_type(2))) float;

__device__ __forceinline__ float sigmoidf_(float x) { return 1.0f / (1.0f + __expf(-x)); }
__device__ __forceinline__ __half2 u2h(unsigned u) { return __builtin_bit_cast(__half2, u); }
__device__ __forceinline__ unsigned packh2(float a, float b) {
    return __builtin_bit_cast(unsigned, __float22half2_rn(make_float2(a, b)));
}

#if __has_builtin(__builtin_amdgcn_cvt_pk_f32_fp8) && __has_builtin(__builtin_amdgcn_cvt_pk_fp8_f32)
#define FP8_HW 1
#else
#define FP8_HW 0
__device__ __forceinline__ unsigned fp8_enc1(float f) {
    unsigned short us = __builtin_bit_cast(unsigned short, __float2half(f));
    unsigned s = (us >> 8) & 0x80u;
    unsigned mag = us & 0x7fffu;
    if (mag < 0x2400u) return s;            // FTZ
    unsigned t = mag - 0x2000u;             // rebias 15->7
    t += 0x3Fu + ((t >> 7) & 1u);           // RNE
    unsigned r = t >> 7;
    if (r > 0x7Eu) r = 0x7Eu;
    return s | r;
}
__device__ __forceinline__ float fp8_dec1(unsigned v) {
    unsigned s = (v & 0x80u) << 8;
    unsigned m = v & 0x7Fu;
    unsigned h = m ? (((m << 7) + 0x2000u) | s) : s;
    return __half2float(__builtin_bit_cast(__half, (unsigned short)h));
}
#endif

// decode 16 fp8 (uint4) and accumulate into 16 f32
__device__ __forceinline__ void acc16(float* a, uint4 v) {
#if FP8_HW
    f32x2 t;
    t = __builtin_amdgcn_cvt_pk_f32_fp8(v.x, false); a[0] += t[0];  a[1] += t[1];
    t = __builtin_amdgcn_cvt_pk_f32_fp8(v.x, true);  a[2] += t[0];  a[3] += t[1];
    t = __builtin_amdgcn_cvt_pk_f32_fp8(v.y, false); a[4] += t[0];  a[5] += t[1];
    t = __builtin_amdgcn_cvt_pk_f32_fp8(v.y, true);  a[6] += t[0];  a[7] += t[1];
    t = __builtin_amdgcn_cvt_pk_f32_fp8(v.z, false); a[8] += t[0];  a[9] += t[1];
    t = __builtin_amdgcn_cvt_pk_f32_fp8(v.z, true);  a[10] += t[0]; a[11] += t[1];
    t = __builtin_amdgcn_cvt_pk_f32_fp8(v.w, false); a[12] += t[0]; a[13] += t[1];
    t = __builtin_amdgcn_cvt_pk_f32_fp8(v.w, true);  a[14] += t[0]; a[15] += t[1];
#else
    unsigned d[4] = {v.x, v.y, v.z, v.w};
#pragma unroll
    for (int q = 0; q < 4; q++)
#pragma unroll
        for (int b = 0; b < 4; b++) a[q * 4 + b] += fp8_dec1((d[q] >> (8 * b)) & 0xffu);
#endif
}

__device__ __forceinline__ unsigned pack4fp8(float a, float b, float c, float d) {
#if FP8_HW
    unsigned r = 0;
    r = __builtin_amdgcn_cvt_pk_fp8_f32(a, b, r, false);
    r = __builtin_amdgcn_cvt_pk_fp8_f32(c, d, r, true);
    return r;
#else
    return fp8_enc1(a) | (fp8_enc1(b) << 8) | (fp8_enc1(c) << 16) | (fp8_enc1(d) << 24);
#endif
}

// ---------------- bucketed CSR build (R9 structure + int4 loads) ----------------
__global__ __launch_bounds__(256) void k_bucket_scatter(const int* __restrict__ src,
                                                        const int* __restrict__ dst, int E,
                                                        int* __restrict__ bucketCnt, int NB,
                                                        unsigned* __restrict__ pairBuf) {
    __shared__ int hist[1024];
    int tid = threadIdx.x;
    for (int t = tid; t < 1024; t += 256) hist[t] = 0;
    __syncthreads();
    int base = blockIdx.x * EPB;
    int end = min(base + EPB, E);
    int cnt4 = (end - base) >> 2;
    const int4* d4 = (const int4*)(dst + base);
    const int4* s4 = (const int4*)(src + base);
    // pass 1: bucket histogram (4 edges per VMEM)
    for (int i = tid; i < cnt4; i += 256) {
        int4 d = d4[i];
        atomicAdd(&hist[d.x >> 7], 1);
        atomicAdd(&hist[d.y >> 7], 1);
        atomicAdd(&hist[d.z >> 7], 1);
        atomicAdd(&hist[d.w >> 7], 1);
    }
    for (int i = base + (cnt4 << 2) + tid; i < end; i += 256)
        atomicAdd(&hist[dst[i] >> 7], 1);
    __syncthreads();
    // reserve global ranges; hist becomes running cursor
    for (int t = tid; t < NB; t += 256) {
        int c = hist[t];
        hist[t] = c ? atomicAdd(&bucketCnt[t], c) : 0;
    }
    __syncthreads();
    // pass 2: place pairs (4 edges per VMEM pair)
    for (int i = tid; i < cnt4; i += 256) {
        int4 d = d4[i];
        int4 s = s4[i];
        int b, p;
        b = d.x >> 7; p = atomicAdd(&hist[b], 1);
        if (p < BUCKET_CAP) pairBuf[(size_t)b * BUCKET_CAP + p] = ((unsigned)s.x << 7) | (unsigned)(d.x & 127);
        b = d.y >> 7; p = atomicAdd(&hist[b], 1);
        if (p < BUCKET_CAP) pairBuf[(size_t)b * BUCKET_CAP + p] = ((unsigned)s.y << 7) | (unsigned)(d.y & 127);
        b = d.z >> 7; p = atomicAdd(&hist[b], 1);
        if (p < BUCKET_CAP) pairBuf[(size_t)b * BUCKET_CAP + p] = ((unsigned)s.z << 7) | (unsigned)(d.z & 127);
        b = d.w >> 7; p = atomicAdd(&hist[b], 1);
        if (p < BUCKET_CAP) pairBuf[(size_t)b * BUCKET_CAP + p] = ((unsigned)s.w << 7) | (unsigned)(d.w & 127);
    }
    for (int i = base + (cnt4 << 2) + tid; i < end; i += 256) {
        int d = dst[i];
        int b = d >> 7;
        int p = atomicAdd(&hist[b], 1);
        if (p < BUCKET_CAP) pairBuf[(size_t)b * BUCKET_CAP + p] = ((unsigned)src[i] << 7) | (unsigned)(d & 127);
    }
}

// single-block exclusive scan of per-bucket totals -> bucketBase; rowptr[n]=total
__global__ __launch_bounds__(1024) void k_scan_buckets(const int* __restrict__ bucketCnt, int NB,
                                                       int* __restrict__ bucketBase,
                                                       int* __restrict__ rowptr, int n) {
    __shared__ int sh[1024];
    int t = threadIdx.x;
    int v = (t < NB) ? min(bucketCnt[t], BUCKET_CAP) : 0;
    sh[t] = v;
    __syncthreads();
    for (int off = 1; off < 1024; off <<= 1) {
        int u = (t >= off) ? sh[t - off] : 0;
        __syncthreads();
        sh[t] += u;
        __syncthreads();
    }
    if (t < NB) bucketBase[t] = sh[t] - v;
    if (t == 1023) rowptr[n] = sh[1023];
}

// fused: per-bucket node hist -> LDS scan -> rowptr/dinv -> place col. One block per bucket.
__global__ __launch_bounds__(256) void k_bucket_place2(const unsigned* __restrict__ pairBuf,
                                                       const int* __restrict__ bucketCnt,
                                                       const int* __restrict__ bucketBase,
                                                       int* __restrict__ rowptr,
                                                       float* __restrict__ dinv,
                                                       int* __restrict__ col, int n) {
    __shared__ int hist[NODES_PER_BUCKET];
    __shared__ int excl[NODES_PER_BUCKET];
    __shared__ int stage[BUCKET_CAP];
    int b = blockIdx.x;
    int tid = threadIdx.x;
    int first = b * NODES_PER_BUCKET;
    if (tid < NODES_PER_BUCKET) hist[tid] = 0;
    __syncthreads();
    int cb = min(bucketCnt[b], BUCKET_CAP);
    const unsigned* p = pairBuf + (size_t)b * BUCKET_CAP;
    for (int e = tid; e < cb; e += 256) atomicAdd(&hist[p[e] & 127], 1);
    __syncthreads();
    int v = (tid < NODES_PER_BUCKET) ? hist[tid] : 0;
    if (tid < NODES_PER_BUCKET) excl[tid] = v;
    __syncthreads();
    for (int off = 1; off < NODES_PER_BUCKET; off <<= 1) {
        int u = (tid < NODES_PER_BUCKET && tid >= off) ? excl[tid - off] : 0;
        __syncthreads();
        if (tid < NODES_PER_BUCKET) excl[tid] += u;
        __syncthreads();
    }
    int base = bucketBase[b];
    if (tid < NODES_PER_BUCKET) {
        int node = first + tid;
        int ex = excl[tid] - v;
        if (node < n) {
            rowptr[node] = base + ex;
            dinv[node] = rsqrtf((float)(v + 1));  // +1 self loop
        }
        hist[tid] = ex;  // reuse as cursor
    }
    __syncthreads();
    for (int e = tid; e < cb; e += 256) {
        unsigned pr = p[e];
        int lpos = atomicAdd(&hist[pr & 127], 1);
        stage[lpos] = (int)(pr >> 7);
    }
    __syncthreads();
    for (int i = tid; i < cb; i += 256) col[base + i] = stage[i];
}

// ---------------- GEMM: Y = (X @ W) * dinv[row], output fp8(e4m3) ----------------
template <int OUTC, bool INHALF>
__global__ __launch_bounds__(256) void k_gemm_scale(const void* __restrict__ Xv,
                                                    const float* __restrict__ W,
                                                    const float* __restrict__ dinv,
                                                    unsigned char* __restrict__ Yb, int n) {
    constexpr int TN = OUTC / 16;  // 8 (128) or 4 (64)
    __shared__ float xs[16][65];
    __shared__ float ws[16 * OUTC];
    int tid = threadIdx.x;
    int row0 = blockIdx.x * 64;
    int tx = tid & 15;
    int ty = tid >> 4;

    float acc[4][TN];
#pragma unroll
    for (int i = 0; i < 4; i++)
#pragma unroll
        for (int j = 0; j < TN; j++) acc[i][j] = 0.0f;

    for (int k0 = 0; k0 < IN_CH; k0 += 16) {
        {
            int r = tid >> 2;
            int kq = (tid & 3) * 4;
            int grow = row0 + r;
            float4 xv = make_float4(0.f, 0.f, 0.f, 0.f);
            if (grow < n) {
                if constexpr (INHALF) {
                    uint2 xu = *(const uint2*)((const unsigned short*)Xv + (size_t)grow * IN_CH + k0 + kq);
                    __half2 p0 = u2h(xu.x), p1 = u2h(xu.y);
                    xv = make_float4(__low2float(p0), __high2float(p0), __low2float(p1), __high2float(p1));
                } else {
                    xv = *(const float4*)((const float*)Xv + (size_t)grow * IN_CH + k0 + kq);
                }
            }
            xs[kq + 0][r] = xv.x;
            xs[kq + 1][r] = xv.y;
            xs[kq + 2][r] = xv.z;
            xs[kq + 3][r] = xv.w;
        }
        {
            const float4* wsrc = (const float4*)(W + k0 * OUTC);
            float4* wdst = (float4*)ws;
#pragma unroll
            for (int j = 0; j < OUTC / 64; j++) wdst[tid + j * 256] = wsrc[tid + j * 256];
        }
        __syncthreads();
#pragma unroll
        for (int kk = 0; kk < 16; kk++) {
            float a[4];
            *(float4*)a = *(const float4*)&xs[kk][ty * 4];
            float bb[TN];
#pragma unroll
            for (int j = 0; j < TN / 4; j++)
                *(float4*)&bb[j * 4] = *(const float4*)&ws[kk * OUTC + tx * TN + j * 4];
#pragma unroll
            for (int i = 0; i < 4; i++)
#pragma unroll
                for (int j = 0; j < TN; j++) acc[i][j] = fmaf(a[i], bb[j], acc[i][j]);
        }
        __syncthreads();
    }
#pragma unroll
    for (int i = 0; i < 4; i++) {
        int grow = row0 + ty * 4 + i;
        if (grow < n) {
            float dvv = dinv[grow];
            if constexpr (TN == 8) {
                uint2 o;
                o.x = pack4fp8(acc[i][0] * dvv, acc[i][1] * dvv, acc[i][2] * dvv, acc[i][3] * dvv);
                o.y = pack4fp8(acc[i][4] * dvv, acc[i][5] * dvv, acc[i][6] * dvv, acc[i][7] * dvv);
                ((uint2*)(Yb + (size_t)grow * 128))[tx] = o;
            } else {
                unsigned o = pack4fp8(acc[i][0] * dvv, acc[i][1] * dvv, acc[i][2] * dvv, acc[i][3] * dvv);
                ((unsigned*)(Yb + (size_t)grow * 64))[tx] = o;
            }
        }
    }
}

// ---------------- aggregation: out = act(dinv[d]*(sum y[s] + y[d]) + b) ----------------
// ONE NODE PER LANE-GROUP + UNROLL-4 (R14): LPE=C/16 lanes own one node's full row
// (16B/lane); NPW=64/LPE nodes per wave. Each lane accumulates its own 16 channels
// (no cross-lane reduce). Loop unrolled x4: 4 independent col loads then 4
// independent gathers in flight -> 1 round trip per 4 edges (was 1 per 2).
template <int C, bool OUTHALF>
__global__ __launch_bounds__(256) void k_agg(const uint4* __restrict__ Y4,
                                             const int* __restrict__ rowptr,
                                             const int* __restrict__ col,
                                             const float* __restrict__ dinv,
                                             const float* __restrict__ bias,
                                             void* __restrict__ out, int n, int zidx) {
    constexpr int LPE = C / 16;     // lanes per row: 8 (C=128) or 4 (C=64)
    constexpr int NPW = 64 / LPE;   // nodes per wave: 8 or 16
    constexpr int RS = C / 16;      // uint4 per row
    int gid = blockIdx.x * blockDim.x + threadIdx.x;
    int wid = gid >> 6;
    int lane = gid & 63;
    int g = lane / LPE;
    int sub = lane % LPE;
    int node = wid * NPW + g;
    bool valid = node < n;
    int nc = valid ? node : 0;
    int s0 = rowptr[nc];
    int s1 = valid ? rowptr[nc + 1] : s0;

    float a0[16], a1[16];
#pragma unroll
    for (int k = 0; k < 16; k++) { a0[k] = 0.f; a1[k] = 0.f; }

    // self loop: every group gathers its own node's row
    {
        int idx = valid ? node : zidx;
        uint4 v = Y4[(size_t)idx * RS + sub];
        acc16(a0, v);
    }
    int e = s0;
    for (; e + 4 <= s1; e += 4) {
        int c0 = col[e];
        int c1 = col[e + 1];
        int c2 = col[e + 2];
        int c3 = col[e + 3];
        uint4 v0 = Y4[(size_t)c0 * RS + sub];
        uint4 v1 = Y4[(size_t)c1 * RS + sub];
        uint4 v2 = Y4[(size_t)c2 * RS + sub];
        uint4 v3 = Y4[(size_t)c3 * RS + sub];
        acc16(a0, v0);
        acc16(a1, v1);
        acc16(a0, v2);
        acc16(a1, v3);
    }
    for (; e < s1; e++) {
        uint4 v = Y4[(size_t)col[e] * RS + sub];
        acc16(a0, v);
    }
#pragma unroll
    for (int k = 0; k < 16; k++) a0[k] += a1[k];

    if (valid) {
        float dv = dinv[node];
        float4 bv[4];
        bv[0] = *(const float4*)&bias[sub * 16];
        bv[1] = *(const float4*)&bias[sub * 16 + 4];
        bv[2] = *(const float4*)&bias[sub * 16 + 8];
        bv[3] = *(const float4*)&bias[sub * 16 + 12];
        float o[16];
#pragma unroll
        for (int q = 0; q < 4; q++) {
            const float* bq = (const float*)&bv[q];
#pragma unroll
            for (int b = 0; b < 4; b++) o[q * 4 + b] = sigmoidf_(a0[q * 4 + b] * dv + bq[b]);
        }
        if constexpr (OUTHALF) {
            constexpr int OR = C / 8;  // uint4 per f16 row
            uint4 h0, h1;
            h0.x = packh2(o[0], o[1]);   h0.y = packh2(o[2], o[3]);
            h0.z = packh2(o[4], o[5]);   h0.w = packh2(o[6], o[7]);
            h1.x = packh2(o[8], o[9]);   h1.y = packh2(o[10], o[11]);
            h1.z = packh2(o[12], o[13]); h1.w = packh2(o[14], o[15]);
            ((uint4*)out)[(size_t)node * OR + sub * 2] = h0;
            ((uint4*)out)[(size_t)node * OR + sub * 2 + 1] = h1;
        } else {
            float* op = (float*)out + (size_t)node * C + sub * 16;
            *(float4*)(op + 0)  = make_float4(o[0], o[1], o[2], o[3]);
            *(float4*)(op + 4)  = make_float4(o[4], o[5], o[6], o[7]);
            *(float4*)(op + 8)  = make_float4(o[8], o[9], o[10], o[11]);
            *(float4*)(op + 12) = make_float4(o[12], o[13], o[14], o[15]);
        }
    }
}

extern "C" void kernel_launch(void* const* d_in, const int* in_sizes, int n_in,
                              void* d_out, int out_size, void* d_ws, size_t ws_size,
                              hipStream_t stream) {
    const float* x  = (const float*)d_in[0];
    const int* eidx = (const int*)d_in[1];
    const float* W1 = (const float*)d_in[2];
    const float* b1 = (const float*)d_in[3];
    const float* W2 = (const float*)d_in[4];
    const float* b2 = (const float*)d_in[5];
    float* out = (float*)d_out;

    int n = in_sizes[0] / IN_CH;
    int E = in_sizes[1] / 2;
    const int* srcv = eidx;
    const int* dstv = eidx + E;
    int NB = (n + NODES_PER_BUCKET - 1) / NODES_PER_BUCKET;  // 782 (must be <=1024)

    char* w = (char*)d_ws;
    auto alloc = [&](size_t bytes) {
        char* p = w;
        w += (bytes + 255) & ~(size_t)255;
        return p;
    };
    int* bucketCnt      = (int*)alloc((size_t)NB * 4);
    int* bucketBase     = (int*)alloc((size_t)NB * 4);
    unsigned* pairBuf   = (unsigned*)alloc((size_t)NB * BUCKET_CAP * 4);
    int* rowptr         = (int*)alloc(((size_t)n + 1) * 4);
    float* dinv         = (float*)alloc((size_t)n * 4);
    int* col            = (int*)alloc((size_t)E * 4);
    unsigned char* y    = (unsigned char*)alloc(((size_t)n + 1) * 128);  // fp8 [n+1][128B]; reused for y2 [n][64B]
    unsigned short* h   = (unsigned short*)alloc((size_t)n * IN_CH * 2); // f16 [n][128]

    hipMemsetAsync(bucketCnt, 0, (size_t)NB * 4, stream);
    // zero row: serves agg1 (row n, 128B rows) and agg2 (row 2n, 64B rows — same bytes)
    hipMemsetAsync(y + (size_t)n * 128, 0, 128, stream);

    int nblk = (E + EPB - 1) / EPB;  // 391
    k_bucket_scatter<<<nblk, 256, 0, stream>>>(srcv, dstv, E, bucketCnt, NB, pairBuf);
    k_scan_buckets<<<1, 1024, 0, stream>>>(bucketCnt, NB, bucketBase, rowptr, n);
    k_bucket_place2<<<NB, 256, 0, stream>>>(pairBuf, bucketCnt, bucketBase, rowptr, dinv, col, n);

    int gemmGrid = (n + 63) / 64;

    // layer 1 (8 nodes/wave, 4 waves/block -> 32 nodes/block)
    k_gemm_scale<128, false><<<gemmGrid, 256, 0, stream>>>(x, W1, dinv, y, n);
    k_agg<128, true><<<(n + 31) / 32, 256, 0, stream>>>((const uint4*)y, rowptr, col, dinv, b1, h, n, n);
    // layer 2 (16 nodes/wave -> 64 nodes/block; y reused as fp8 [n][64B], zero row at 2n)
    k_gemm_scale<64, true><<<gemmGrid, 256, 0, stream>>>(h, W2, dinv, y, n);
    k_agg<64, false><<<(n + 63) / 64, 256, 0, stream>>>((const uint4*)y, rowptr, col, dinv, b2, out, n, 2 * n);
}

// Round 15
// 241.171 us; speedup vs baseline: 1.4906x; 1.0769x over previous
//
#include <hip/hip_runtime.h>
#include <hip/hip_bf16.h>
#include <hip/hip_fp16.h>

#define IN_CH 128
#define NODES_PER_BUCKET 128
#define BUCKET_CAP 5120     // mean 4096, sigma ~64; 16-sigma headroom
#define EPB 8192            // edges per scatter block (391 blocks)

using f32x2 = __attribute__((ext_vector_type(2))) float;

__device__ __forceinline__ float sigmoidf_(float x) { return 1.0f / (1.0f + __expf(-x)); }
__device__ __forceinline__ __half2 u2h(unsigned u) { return __builtin_bit_cast(__half2, u); }
__device__ __forceinline__ unsigned packh2(float a, float b) {
    return __builtin_bit_cast(unsigned, __float22half2_rn(make_float2(a, b)));
}

#if __has_builtin(__builtin_amdgcn_cvt_pk_f32_fp8) && __has_builtin(__builtin_amdgcn_cvt_pk_fp8_f32)
#define FP8_HW 1
#else
#define FP8_HW 0
__device__ __forceinline__ unsigned fp8_enc1(float f) {
    unsigned short us = __builtin_bit_cast(unsigned short, __float2half(f));
    unsigned s = (us >> 8) & 0x80u;
    unsigned mag = us & 0x7fffu;
    if (mag < 0x2400u) return s;            // FTZ
    unsigned t = mag - 0x2000u;             // rebias 15->7
    t += 0x3Fu + ((t >> 7) & 1u);           // RNE
    unsigned r = t >> 7;
    if (r > 0x7Eu) r = 0x7Eu;
    return s | r;
}
__device__ __forceinline__ float fp8_dec1(unsigned v) {
    unsigned s = (v & 0x80u) << 8;
    unsigned m = v & 0x7Fu;
    unsigned h = m ? (((m << 7) + 0x2000u) | s) : s;
    return __half2float(__builtin_bit_cast(__half, (unsigned short)h));
}
#endif

// decode 16 fp8 (uint4) and accumulate into 16 f32
__device__ __forceinline__ void acc16(float* a, uint4 v) {
#if FP8_HW
    f32x2 t;
    t = __builtin_amdgcn_cvt_pk_f32_fp8(v.x, false); a[0] += t[0];  a[1] += t[1];
    t = __builtin_amdgcn_cvt_pk_f32_fp8(v.x, true);  a[2] += t[0];  a[3] += t[1];
    t = __builtin_amdgcn_cvt_pk_f32_fp8(v.y, false); a[4] += t[0];  a[5] += t[1];
    t = __builtin_amdgcn_cvt_pk_f32_fp8(v.y, true);  a[6] += t[0];  a[7] += t[1];
    t = __builtin_amdgcn_cvt_pk_f32_fp8(v.z, false); a[8] += t[0];  a[9] += t[1];
    t = __builtin_amdgcn_cvt_pk_f32_fp8(v.z, true);  a[10] += t[0]; a[11] += t[1];
    t = __builtin_amdgcn_cvt_pk_f32_fp8(v.w, false); a[12] += t[0]; a[13] += t[1];
    t = __builtin_amdgcn_cvt_pk_f32_fp8(v.w, true);  a[14] += t[0]; a[15] += t[1];
#else
    unsigned d[4] = {v.x, v.y, v.z, v.w};
#pragma unroll
    for (int q = 0; q < 4; q++)
#pragma unroll
        for (int b = 0; b < 4; b++) a[q * 4 + b] += fp8_dec1((d[q] >> (8 * b)) & 0xffu);
#endif
}

__device__ __forceinline__ unsigned pack4fp8(float a, float b, float c, float d) {
#if FP8_HW
    unsigned r = 0;
    r = __builtin_amdgcn_cvt_pk_fp8_f32(a, b, r, false);
    r = __builtin_amdgcn_cvt_pk_fp8_f32(c, d, r, true);
    return r;
#else
    return fp8_enc1(a) | (fp8_enc1(b) << 8) | (fp8_enc1(c) << 16) | (fp8_enc1(d) << 24);
#endif
}

// ---------------- bucketed CSR build: single-pass register-rank scatter ----------------
// Pass 1: each thread holds 32 edges (8 masked int4 iters) in registers, computes
// in-bucket rank via ONE LDS atomic per edge. Reserve converts hist->global base.
// Pass 2: pure writes (no atomics, no edge re-read). All register arrays are
// constant-indexed (no scratch).
__global__ __launch_bounds__(256) void k_bucket_scatter(const int* __restrict__ src,
                                                        const int* __restrict__ dst, int E,
                                                        int* __restrict__ bucketCnt, int NB,
                                                        unsigned* __restrict__ pairBuf) {
    __shared__ int hist[1024];
    int tid = threadIdx.x;
    for (int t = tid; t < 1024; t += 256) hist[t] = 0;
    __syncthreads();
    int base = blockIdx.x * EPB;
    int end = min(base + EPB, E);
    int cnt = end - base;
    int cnt4 = cnt >> 2;
    const int4* d4 = (const int4*)(dst + base);
    const int4* s4 = (const int4*)(src + base);

    unsigned pr[8][4];   // packed pairs
    unsigned rkb[8][4];  // (rank<<10)|bucket
#pragma unroll
    for (int j = 0; j < 8; j++) {
        int i = tid + j * 256;
        if (i < cnt4) {
            int4 d = d4[i];
            int4 s = s4[i];
            int b, r;
            b = d.x >> 7; r = atomicAdd(&hist[b], 1);
            pr[j][0] = ((unsigned)s.x << 7) | (unsigned)(d.x & 127); rkb[j][0] = ((unsigned)r << 10) | (unsigned)b;
            b = d.y >> 7; r = atomicAdd(&hist[b], 1);
            pr[j][1] = ((unsigned)s.y << 7) | (unsigned)(d.y & 127); rkb[j][1] = ((unsigned)r << 10) | (unsigned)b;
            b = d.z >> 7; r = atomicAdd(&hist[b], 1);
            pr[j][2] = ((unsigned)s.z << 7) | (unsigned)(d.z & 127); rkb[j][2] = ((unsigned)r << 10) | (unsigned)b;
            b = d.w >> 7; r = atomicAdd(&hist[b], 1);
            pr[j][3] = ((unsigned)s.w << 7) | (unsigned)(d.w & 127); rkb[j][3] = ((unsigned)r << 10) | (unsigned)b;
        }
    }
    // scalar tail (< 4 edges)
    unsigned prT = 0, rkbT = 0;
    bool hasT = false;
    {
        int tl = cnt & 3;
        if (tid < tl) {
            int i = base + (cnt4 << 2) + tid;
            int d = dst[i];
            int b = d >> 7;
            int r = atomicAdd(&hist[b], 1);
            prT = ((unsigned)src[i] << 7) | (unsigned)(d & 127);
            rkbT = ((unsigned)r << 10) | (unsigned)b;
            hasT = true;
        }
    }
    __syncthreads();
    for (int t = tid; t < NB; t += 256) {
        int c = hist[t];
        hist[t] = c ? atomicAdd(&bucketCnt[t], c) : 0;  // hist becomes global base
    }
    __syncthreads();
#pragma unroll
    for (int j = 0; j < 8; j++) {
        int i = tid + j * 256;
        if (i < cnt4) {
#pragma unroll
            for (int q = 0; q < 4; q++) {
                unsigned t = rkb[j][q];
                int b = (int)(t & 1023u);
                int pos = hist[b] + (int)(t >> 10);
                if (pos < BUCKET_CAP) pairBuf[(size_t)b * BUCKET_CAP + pos] = pr[j][q];
            }
        }
    }
    if (hasT) {
        int b = (int)(rkbT & 1023u);
        int pos = hist[b] + (int)(rkbT >> 10);
        if (pos < BUCKET_CAP) pairBuf[(size_t)b * BUCKET_CAP + pos] = prT;
    }
}

// single-block exclusive scan of per-bucket totals -> bucketBase; rowptr[n]=total
__global__ __launch_bounds__(1024) void k_scan_buckets(const int* __restrict__ bucketCnt, int NB,
                                                       int* __restrict__ bucketBase,
                                                       int* __restrict__ rowptr, int n) {
    __shared__ int sh[1024];
    int t = threadIdx.x;
    int v = (t < NB) ? min(bucketCnt[t], BUCKET_CAP) : 0;
    sh[t] = v;
    __syncthreads();
    for (int off = 1; off < 1024; off <<= 1) {
        int u = (t >= off) ? sh[t - off] : 0;
        __syncthreads();
        sh[t] += u;
        __syncthreads();
    }
    if (t < NB) bucketBase[t] = sh[t] - v;
    if (t == 1023) rowptr[n] = sh[1023];
}

// fused: per-bucket node hist -> LDS scan -> rowptr/dinv -> place col. One block per bucket.
__global__ __launch_bounds__(256) void k_bucket_place2(const unsigned* __restrict__ pairBuf,
                                                       const int* __restrict__ bucketCnt,
                                                       const int* __restrict__ bucketBase,
                                                       int* __restrict__ rowptr,
                                                       float* __restrict__ dinv,
                                                       int* __restrict__ col, int n) {
    __shared__ int hist[NODES_PER_BUCKET];
    __shared__ int excl[NODES_PER_BUCKET];
    __shared__ int stage[BUCKET_CAP];
    int b = blockIdx.x;
    int tid = threadIdx.x;
    int first = b * NODES_PER_BUCKET;
    if (tid < NODES_PER_BUCKET) hist[tid] = 0;
    __syncthreads();
    int cb = min(bucketCnt[b], BUCKET_CAP);
    const unsigned* p = pairBuf + (size_t)b * BUCKET_CAP;
    for (int e = tid; e < cb; e += 256) atomicAdd(&hist[p[e] & 127], 1);
    __syncthreads();
    int v = (tid < NODES_PER_BUCKET) ? hist[tid] : 0;
    if (tid < NODES_PER_BUCKET) excl[tid] = v;
    __syncthreads();
    for (int off = 1; off < NODES_PER_BUCKET; off <<= 1) {
        int u = (tid < NODES_PER_BUCKET && tid >= off) ? excl[tid - off] : 0;
        __syncthreads();
        if (tid < NODES_PER_BUCKET) excl[tid] += u;
        __syncthreads();
    }
    int base = bucketBase[b];
    if (tid < NODES_PER_BUCKET) {
        int node = first + tid;
        int ex = excl[tid] - v;
        if (node < n) {
            rowptr[node] = base + ex;
            dinv[node] = rsqrtf((float)(v + 1));  // +1 self loop
        }
        hist[tid] = ex;  // reuse as cursor
    }
    __syncthreads();
    for (int e = tid; e < cb; e += 256) {
        unsigned pr = p[e];
        int lpos = atomicAdd(&hist[pr & 127], 1);
        stage[lpos] = (int)(pr >> 7);
    }
    __syncthreads();
    for (int i = tid; i < cb; i += 256) col[base + i] = stage[i];
}

// ---------------- GEMM: Y = (X @ W) * dinv[row], output fp8(e4m3) ----------------
template <int OUTC, bool INHALF>
__global__ __launch_bounds__(256) void k_gemm_scale(const void* __restrict__ Xv,
                                                    const float* __restrict__ W,
                                                    const float* __restrict__ dinv,
                                                    unsigned char* __restrict__ Yb, int n) {
    constexpr int TN = OUTC / 16;  // 8 (128) or 4 (64)
    __shared__ float xs[16][65];
    __shared__ float ws[16 * OUTC];
    int tid = threadIdx.x;
    int row0 = blockIdx.x * 64;
    int tx = tid & 15;
    int ty = tid >> 4;

    float acc[4][TN];
#pragma unroll
    for (int i = 0; i < 4; i++)
#pragma unroll
        for (int j = 0; j < TN; j++) acc[i][j] = 0.0f;

    for (int k0 = 0; k0 < IN_CH; k0 += 16) {
        {
            int r = tid >> 2;
            int kq = (tid & 3) * 4;
            int grow = row0 + r;
            float4 xv = make_float4(0.f, 0.f, 0.f, 0.f);
            if (grow < n) {
                if constexpr (INHALF) {
                    uint2 xu = *(const uint2*)((const unsigned short*)Xv + (size_t)grow * IN_CH + k0 + kq);
                    __half2 p0 = u2h(xu.x), p1 = u2h(xu.y);
                    xv = make_float4(__low2float(p0), __high2float(p0), __low2float(p1), __high2float(p1));
                } else {
                    xv = *(const float4*)((const float*)Xv + (size_t)grow * IN_CH + k0 + kq);
                }
            }
            xs[kq + 0][r] = xv.x;
            xs[kq + 1][r] = xv.y;
            xs[kq + 2][r] = xv.z;
            xs[kq + 3][r] = xv.w;
        }
        {
            const float4* wsrc = (const float4*)(W + k0 * OUTC);
            float4* wdst = (float4*)ws;
#pragma unroll
            for (int j = 0; j < OUTC / 64; j++) wdst[tid + j * 256] = wsrc[tid + j * 256];
        }
        __syncthreads();
#pragma unroll
        for (int kk = 0; kk < 16; kk++) {
            float a[4];
            *(float4*)a = *(const float4*)&xs[kk][ty * 4];
            float bb[TN];
#pragma unroll
            for (int j = 0; j < TN / 4; j++)
                *(float4*)&bb[j * 4] = *(const float4*)&ws[kk * OUTC + tx * TN + j * 4];
#pragma unroll
            for (int i = 0; i < 4; i++)
#pragma unroll
                for (int j = 0; j < TN; j++) acc[i][j] = fmaf(a[i], bb[j], acc[i][j]);
        }
        __syncthreads();
    }
#pragma unroll
    for (int i = 0; i < 4; i++) {
        int grow = row0 + ty * 4 + i;
        if (grow < n) {
            float dvv = dinv[grow];
            if constexpr (TN == 8) {
                uint2 o;
                o.x = pack4fp8(acc[i][0] * dvv, acc[i][1] * dvv, acc[i][2] * dvv, acc[i][3] * dvv);
                o.y = pack4fp8(acc[i][4] * dvv, acc[i][5] * dvv, acc[i][6] * dvv, acc[i][7] * dvv);
                ((uint2*)(Yb + (size_t)grow * 128))[tx] = o;
            } else {
                unsigned o = pack4fp8(acc[i][0] * dvv, acc[i][1] * dvv, acc[i][2] * dvv, acc[i][3] * dvv);
                ((unsigned*)(Yb + (size_t)grow * 64))[tx] = o;
            }
        }
    }
}

// ---------------- aggregation: out = act(dinv[d]*(sum y[s] + y[d]) + b) ----------------
// ONE NODE PER LANE-GROUP + UNROLL-8 (R15): LPE=C/16 lanes own one node's row
// (16B/lane); NPW=64/LPE nodes per wave. 8 independent col loads then 8 independent
// gathers in flight before any wait; tail = one masked 8-wide iteration (no serial
// scalar tail). Single accumulator bank keeps VGPR ~70 (7 waves/SIMD).
template <int C, bool OUTHALF>
__global__ __launch_bounds__(256) void k_agg(const uint4* __restrict__ Y4,
                                             const int* __restrict__ rowptr,
                                             const int* __restrict__ col,
                                             const float* __restrict__ dinv,
                                             const float* __restrict__ bias,
                                             void* __restrict__ out, int n, int zidx) {
    constexpr int LPE = C / 16;     // lanes per row: 8 (C=128) or 4 (C=64)
    constexpr int NPW = 64 / LPE;   // nodes per wave: 8 or 16
    constexpr int RS = C / 16;      // uint4 per row
    int gid = blockIdx.x * blockDim.x + threadIdx.x;
    int wid = gid >> 6;
    int lane = gid & 63;
    int g = lane / LPE;
    int sub = lane % LPE;
    int node = wid * NPW + g;
    bool valid = node < n;
    int nc = valid ? node : 0;
    int s0 = rowptr[nc];
    int s1 = valid ? rowptr[nc + 1] : s0;

    float a0[16];
#pragma unroll
    for (int k = 0; k < 16; k++) a0[k] = 0.f;

    // self loop: every group gathers its own node's row
    {
        int idx = valid ? node : zidx;
        uint4 v = Y4[(size_t)idx * RS + sub];
        acc16(a0, v);
    }
    int e = s0;
    for (; e + 8 <= s1; e += 8) {
        int c0 = col[e];
        int c1 = col[e + 1];
        int c2 = col[e + 2];
        int c3 = col[e + 3];
        int c4 = col[e + 4];
        int c5 = col[e + 5];
        int c6 = col[e + 6];
        int c7 = col[e + 7];
        uint4 v0 = Y4[(size_t)c0 * RS + sub];
        uint4 v1 = Y4[(size_t)c1 * RS + sub];
        uint4 v2 = Y4[(size_t)c2 * RS + sub];
        uint4 v3 = Y4[(size_t)c3 * RS + sub];
        uint4 v4 = Y4[(size_t)c4 * RS + sub];
        uint4 v5 = Y4[(size_t)c5 * RS + sub];
        uint4 v6 = Y4[(size_t)c6 * RS + sub];
        uint4 v7 = Y4[(size_t)c7 * RS + sub];
        acc16(a0, v0);
        acc16(a0, v1);
        acc16(a0, v2);
        acc16(a0, v3);
        acc16(a0, v4);
        acc16(a0, v5);
        acc16(a0, v6);
        acc16(a0, v7);
    }
    if (e < s1) {  // masked 8-wide tail: all remaining (<8) edges in one parallel batch
        int i0 = min(e + 0, s1 - 1), i1 = min(e + 1, s1 - 1);
        int i2 = min(e + 2, s1 - 1), i3 = min(e + 3, s1 - 1);
        int i4 = min(e + 4, s1 - 1), i5 = min(e + 5, s1 - 1);
        int i6 = min(e + 6, s1 - 1), i7 = min(e + 7, s1 - 1);
        int c0 = (e + 0 < s1) ? col[i0] : zidx;
        int c1 = (e + 1 < s1) ? col[i1] : zidx;
        int c2 = (e + 2 < s1) ? col[i2] : zidx;
        int c3 = (e + 3 < s1) ? col[i3] : zidx;
        int c4 = (e + 4 < s1) ? col[i4] : zidx;
        int c5 = (e + 5 < s1) ? col[i5] : zidx;
        int c6 = (e + 6 < s1) ? col[i6] : zidx;
        int c7 = (e + 7 < s1) ? col[i7] : zidx;
        uint4 v0 = Y4[(size_t)c0 * RS + sub];
        uint4 v1 = Y4[(size_t)c1 * RS + sub];
        uint4 v2 = Y4[(size_t)c2 * RS + sub];
        uint4 v3 = Y4[(size_t)c3 * RS + sub];
        uint4 v4 = Y4[(size_t)c4 * RS + sub];
        uint4 v5 = Y4[(size_t)c5 * RS + sub];
        uint4 v6 = Y4[(size_t)c6 * RS + sub];
        uint4 v7 = Y4[(size_t)c7 * RS + sub];
        acc16(a0, v0);
        acc16(a0, v1);
        acc16(a0, v2);
        acc16(a0, v3);
        acc16(a0, v4);
        acc16(a0, v5);
        acc16(a0, v6);
        acc16(a0, v7);
    }

    if (valid) {
        float dv = dinv[node];
        float4 bv[4];
        bv[0] = *(const float4*)&bias[sub * 16];
        bv[1] = *(const float4*)&bias[sub * 16 + 4];
        bv[2] = *(const float4*)&bias[sub * 16 + 8];
        bv[3] = *(const float4*)&bias[sub * 16 + 12];
        float o[16];
#pragma unroll
        for (int q = 0; q < 4; q++) {
            const float* bq = (const float*)&bv[q];
#pragma unroll
            for (int b = 0; b < 4; b++) o[q * 4 + b] = sigmoidf_(a0[q * 4 + b] * dv + bq[b]);
        }
        if constexpr (OUTHALF) {
            constexpr int OR = C / 8;  // uint4 per f16 row
            uint4 h0, h1;
            h0.x = packh2(o[0], o[1]);   h0.y = packh2(o[2], o[3]);
            h0.z = packh2(o[4], o[5]);   h0.w = packh2(o[6], o[7]);
            h1.x = packh2(o[8], o[9]);   h1.y = packh2(o[10], o[11]);
            h1.z = packh2(o[12], o[13]); h1.w = packh2(o[14], o[15]);
            ((uint4*)out)[(size_t)node * OR + sub * 2] = h0;
            ((uint4*)out)[(size_t)node * OR + sub * 2 + 1] = h1;
        } else {
            float* op = (float*)out + (size_t)node * C + sub * 16;
            *(float4*)(op + 0)  = make_float4(o[0], o[1], o[2], o[3]);
            *(float4*)(op + 4)  = make_float4(o[4], o[5], o[6], o[7]);
            *(float4*)(op + 8)  = make_float4(o[8], o[9], o[10], o[11]);
            *(float4*)(op + 12) = make_float4(o[12], o[13], o[14], o[15]);
        }
    }
}

extern "C" void kernel_launch(void* const* d_in, const int* in_sizes, int n_in,
                              void* d_out, int out_size, void* d_ws, size_t ws_size,
                              hipStream_t stream) {
    const float* x  = (const float*)d_in[0];
    const int* eidx = (const int*)d_in[1];
    const float* W1 = (const float*)d_in[2];
    const float* b1 = (const float*)d_in[3];
    const float* W2 = (const float*)d_in[4];
    const float* b2 = (const float*)d_in[5];
    float* out = (float*)d_out;

    int n = in_sizes[0] / IN_CH;
    int E = in_sizes[1] / 2;
    const int* srcv = eidx;
    const int* dstv = eidx + E;
    int NB = (n + NODES_PER_BUCKET - 1) / NODES_PER_BUCKET;  // 782 (must be <=1024)

    char* w = (char*)d_ws;
    auto alloc = [&](size_t bytes) {
        char* p = w;
        w += (bytes + 255) & ~(size_t)255;
        return p;
    };
    int* bucketCnt      = (int*)alloc((size_t)NB * 4);
    int* bucketBase     = (int*)alloc((size_t)NB * 4);
    unsigned* pairBuf   = (unsigned*)alloc((size_t)NB * BUCKET_CAP * 4);
    int* rowptr         = (int*)alloc(((size_t)n + 1) * 4);
    float* dinv         = (float*)alloc((size_t)n * 4);
    int* col            = (int*)alloc((size_t)E * 4);
    unsigned char* y    = (unsigned char*)alloc(((size_t)n + 1) * 128);  // fp8 [n+1][128B]; reused for y2 [n][64B]
    unsigned short* h   = (unsigned short*)alloc((size_t)n * IN_CH * 2); // f16 [n][128]

    hipMemsetAsync(bucketCnt, 0, (size_t)NB * 4, stream);
    // zero row: serves agg1 (row n, 128B rows) and agg2 (row 2n, 64B rows — same bytes)
    hipMemsetAsync(y + (size_t)n * 128, 0, 128, stream);

    int nblk = (E + EPB - 1) / EPB;  // 391
    k_bucket_scatter<<<nblk, 256, 0, stream>>>(srcv, dstv, E, bucketCnt, NB, pairBuf);
    k_scan_buckets<<<1, 1024, 0, stream>>>(bucketCnt, NB, bucketBase, rowptr, n);
    k_bucket_place2<<<NB, 256, 0, stream>>>(pairBuf, bucketCnt, bucketBase, rowptr, dinv, col, n);

    int gemmGrid = (n + 63) / 64;

    // layer 1 (8 nodes/wave, 4 waves/block -> 32 nodes/block)
    k_gemm_scale<128, false><<<gemmGrid, 256, 0, stream>>>(x, W1, dinv, y, n);
    k_agg<128, true><<<(n + 31) / 32, 256, 0, stream>>>((const uint4*)y, rowptr, col, dinv, b1, h, n, n);
    // layer 2 (16 nodes/wave -> 64 nodes/block; y reused as fp8 [n][64B], zero row at 2n)
    k_gemm_scale<64, true><<<gemmGrid, 256, 0, stream>>>(h, W2, dinv, y, n);
    k_agg<64, false><<<(n + 63) / 64, 256, 0, stream>>>((const uint4*)y, rowptr, col, dinv, b2, out, n, 2 * n);
}

// Round 16
// 221.840 us; speedup vs baseline: 1.6205x; 1.0871x over previous
//
#include <hip/hip_runtime.h>
#include <hip/hip_bf16.h>
#include <hip/hip_fp16.h>

#define IN_CH 128
#define NODES_PER_BUCKET 128
#define BUCKET_CAP 5120     // mean 4096, sigma ~64; 16-sigma headroom
#define EPB 8192            // edges per scatter block (391 blocks)

using f32x2 = __attribute__((ext_vector_type(2))) float;
using f32x4 = __attribute__((ext_vector_type(4))) float;
using f16x8 = __attribute__((ext_vector_type(8))) _Float16;

__device__ __forceinline__ float sigmoidf_(float x) { return 1.0f / (1.0f + __expf(-x)); }
__device__ __forceinline__ __half2 u2h(unsigned u) { return __builtin_bit_cast(__half2, u); }
__device__ __forceinline__ unsigned packh2(float a, float b) {
    return __builtin_bit_cast(unsigned, __float22half2_rn(make_float2(a, b)));
}

#if __has_builtin(__builtin_amdgcn_cvt_pk_f32_fp8) && __has_builtin(__builtin_amdgcn_cvt_pk_fp8_f32)
#define FP8_HW 1
#else
#define FP8_HW 0
__device__ __forceinline__ unsigned fp8_enc1(float f) {
    unsigned short us = __builtin_bit_cast(unsigned short, __float2half(f));
    unsigned s = (us >> 8) & 0x80u;
    unsigned mag = us & 0x7fffu;
    if (mag < 0x2400u) return s;            // FTZ
    unsigned t = mag - 0x2000u;             // rebias 15->7
    t += 0x3Fu + ((t >> 7) & 1u);           // RNE
    unsigned r = t >> 7;
    if (r > 0x7Eu) r = 0x7Eu;
    return s | r;
}
__device__ __forceinline__ float fp8_dec1(unsigned v) {
    unsigned s = (v & 0x80u) << 8;
    unsigned m = v & 0x7Fu;
    unsigned h = m ? (((m << 7) + 0x2000u) | s) : s;
    return __half2float(__builtin_bit_cast(__half, (unsigned short)h));
}
#endif

// decode 16 fp8 (uint4) and accumulate into 16 f32
__device__ __forceinline__ void acc16(float* a, uint4 v) {
#if FP8_HW
    f32x2 t;
    t = __builtin_amdgcn_cvt_pk_f32_fp8(v.x, false); a[0] += t[0];  a[1] += t[1];
    t = __builtin_amdgcn_cvt_pk_f32_fp8(v.x, true);  a[2] += t[0];  a[3] += t[1];
    t = __builtin_amdgcn_cvt_pk_f32_fp8(v.y, false); a[4] += t[0];  a[5] += t[1];
    t = __builtin_amdgcn_cvt_pk_f32_fp8(v.y, true);  a[6] += t[0];  a[7] += t[1];
    t = __builtin_amdgcn_cvt_pk_f32_fp8(v.z, false); a[8] += t[0];  a[9] += t[1];
    t = __builtin_amdgcn_cvt_pk_f32_fp8(v.z, true);  a[10] += t[0]; a[11] += t[1];
    t = __builtin_amdgcn_cvt_pk_f32_fp8(v.w, false); a[12] += t[0]; a[13] += t[1];
    t = __builtin_amdgcn_cvt_pk_f32_fp8(v.w, true);  a[14] += t[0]; a[15] += t[1];
#else
    unsigned d[4] = {v.x, v.y, v.z, v.w};
#pragma unroll
    for (int q = 0; q < 4; q++)
#pragma unroll
        for (int b = 0; b < 4; b++) a[q * 4 + b] += fp8_dec1((d[q] >> (8 * b)) & 0xffu);
#endif
}

__device__ __forceinline__ unsigned pack4fp8(float a, float b, float c, float d) {
#if FP8_HW
    unsigned r = 0;
    r = __builtin_amdgcn_cvt_pk_fp8_f32(a, b, r, false);
    r = __builtin_amdgcn_cvt_pk_fp8_f32(c, d, r, true);
    return r;
#else
    return fp8_enc1(a) | (fp8_enc1(b) << 8) | (fp8_enc1(c) << 16) | (fp8_enc1(d) << 24);
#endif
}

// ---------------- bucketed CSR build: single-pass register-rank scatter ----------------
__global__ __launch_bounds__(256) void k_bucket_scatter(const int* __restrict__ src,
                                                        const int* __restrict__ dst, int E,
                                                        int* __restrict__ bucketCnt, int NB,
                                                        unsigned* __restrict__ pairBuf) {
    __shared__ int hist[1024];
    int tid = threadIdx.x;
    for (int t = tid; t < 1024; t += 256) hist[t] = 0;
    __syncthreads();
    int base = blockIdx.x * EPB;
    int end = min(base + EPB, E);
    int cnt = end - base;
    int cnt4 = cnt >> 2;
    const int4* d4 = (const int4*)(dst + base);
    const int4* s4 = (const int4*)(src + base);

    unsigned pr[8][4];   // packed pairs
    unsigned rkb[8][4];  // (rank<<10)|bucket
#pragma unroll
    for (int j = 0; j < 8; j++) {
        int i = tid + j * 256;
        if (i < cnt4) {
            int4 d = d4[i];
            int4 s = s4[i];
            int b, r;
            b = d.x >> 7; r = atomicAdd(&hist[b], 1);
            pr[j][0] = ((unsigned)s.x << 7) | (unsigned)(d.x & 127); rkb[j][0] = ((unsigned)r << 10) | (unsigned)b;
            b = d.y >> 7; r = atomicAdd(&hist[b], 1);
            pr[j][1] = ((unsigned)s.y << 7) | (unsigned)(d.y & 127); rkb[j][1] = ((unsigned)r << 10) | (unsigned)b;
            b = d.z >> 7; r = atomicAdd(&hist[b], 1);
            pr[j][2] = ((unsigned)s.z << 7) | (unsigned)(d.z & 127); rkb[j][2] = ((unsigned)r << 10) | (unsigned)b;
            b = d.w >> 7; r = atomicAdd(&hist[b], 1);
            pr[j][3] = ((unsigned)s.w << 7) | (unsigned)(d.w & 127); rkb[j][3] = ((unsigned)r << 10) | (unsigned)b;
        }
    }
    unsigned prT = 0, rkbT = 0;
    bool hasT = false;
    {
        int tl = cnt & 3;
        if (tid < tl) {
            int i = base + (cnt4 << 2) + tid;
            int d = dst[i];
            int b = d >> 7;
            int r = atomicAdd(&hist[b], 1);
            prT = ((unsigned)src[i] << 7) | (unsigned)(d & 127);
            rkbT = ((unsigned)r << 10) | (unsigned)b;
            hasT = true;
        }
    }
    __syncthreads();
    for (int t = tid; t < NB; t += 256) {
        int c = hist[t];
        hist[t] = c ? atomicAdd(&bucketCnt[t], c) : 0;  // hist becomes global base
    }
    __syncthreads();
#pragma unroll
    for (int j = 0; j < 8; j++) {
        int i = tid + j * 256;
        if (i < cnt4) {
#pragma unroll
            for (int q = 0; q < 4; q++) {
                unsigned t = rkb[j][q];
                int b = (int)(t & 1023u);
                int pos = hist[b] + (int)(t >> 10);
                if (pos < BUCKET_CAP) pairBuf[(size_t)b * BUCKET_CAP + pos] = pr[j][q];
            }
        }
    }
    if (hasT) {
        int b = (int)(rkbT & 1023u);
        int pos = hist[b] + (int)(rkbT >> 10);
        if (pos < BUCKET_CAP) pairBuf[(size_t)b * BUCKET_CAP + pos] = prT;
    }
}

// single-block exclusive scan of per-bucket totals -> bucketBase; rowptr[n]=total
__global__ __launch_bounds__(1024) void k_scan_buckets(const int* __restrict__ bucketCnt, int NB,
                                                       int* __restrict__ bucketBase,
                                                       int* __restrict__ rowptr, int n) {
    __shared__ int sh[1024];
    int t = threadIdx.x;
    int v = (t < NB) ? min(bucketCnt[t], BUCKET_CAP) : 0;
    sh[t] = v;
    __syncthreads();
    for (int off = 1; off < 1024; off <<= 1) {
        int u = (t >= off) ? sh[t - off] : 0;
        __syncthreads();
        sh[t] += u;
        __syncthreads();
    }
    if (t < NB) bucketBase[t] = sh[t] - v;
    if (t == 1023) rowptr[n] = sh[1023];
}

// fused: per-bucket node hist -> LDS scan -> rowptr/dinv -> place col. One block per bucket.
__global__ __launch_bounds__(256) void k_bucket_place2(const unsigned* __restrict__ pairBuf,
                                                       const int* __restrict__ bucketCnt,
                                                       const int* __restrict__ bucketBase,
                                                       int* __restrict__ rowptr,
                                                       float* __restrict__ dinv,
                                                       int* __restrict__ col, int n) {
    __shared__ int hist[NODES_PER_BUCKET];
    __shared__ int excl[NODES_PER_BUCKET];
    __shared__ int stage[BUCKET_CAP];
    int b = blockIdx.x;
    int tid = threadIdx.x;
    int first = b * NODES_PER_BUCKET;
    if (tid < NODES_PER_BUCKET) hist[tid] = 0;
    __syncthreads();
    int cb = min(bucketCnt[b], BUCKET_CAP);
    const unsigned* p = pairBuf + (size_t)b * BUCKET_CAP;
    for (int e = tid; e < cb; e += 256) atomicAdd(&hist[p[e] & 127], 1);
    __syncthreads();
    int v = (tid < NODES_PER_BUCKET) ? hist[tid] : 0;
    if (tid < NODES_PER_BUCKET) excl[tid] = v;
    __syncthreads();
    for (int off = 1; off < NODES_PER_BUCKET; off <<= 1) {
        int u = (tid < NODES_PER_BUCKET && tid >= off) ? excl[tid - off] : 0;
        __syncthreads();
        if (tid < NODES_PER_BUCKET) excl[tid] += u;
        __syncthreads();
    }
    int base = bucketBase[b];
    if (tid < NODES_PER_BUCKET) {
        int node = first + tid;
        int ex = excl[tid] - v;
        if (node < n) {
            rowptr[node] = base + ex;
            dinv[node] = rsqrtf((float)(v + 1));  // +1 self loop
        }
        hist[tid] = ex;  // reuse as cursor
    }
    __syncthreads();
    for (int e = tid; e < cb; e += 256) {
        unsigned pr = p[e];
        int lpos = atomicAdd(&hist[pr & 127], 1);
        stage[lpos] = (int)(pr >> 7);
    }
    __syncthreads();
    for (int i = tid; i < cb; i += 256) col[base + i] = stage[i];
}

// ---------------- weight prep: wT[n][k] = (f16) W[k][n] ----------------
__global__ __launch_bounds__(256) void k_wprep(const float* __restrict__ W1,
                                               const float* __restrict__ W2,
                                               _Float16* __restrict__ wT1,
                                               _Float16* __restrict__ wT2) {
    int i = blockIdx.x * 256 + threadIdx.x;
    if (i < 128 * 128) {
        int nn = i >> 7, k = i & 127;
        wT1[i] = (_Float16)W1[k * 128 + nn];
    }
    if (i < 64 * 128) {
        int nn = i >> 7, k = i & 127;
        wT2[i] = (_Float16)W2[k * 64 + nn];
    }
}

// ---------------- MFMA GEMM: Y = (X @ W) * dinv[row], output fp8(e4m3) ----------------
// mfma_f32_16x16x32_f16 with SWAPPED operands: A = wT tile (rows = out-channel n),
// B = X rows (cols = node m). D: col=lane&15 = m, row=(lane>>4)*4+reg = n-in-tile.
// => lane (q,tx) owns output row m=r0+tx, channels n = nt*16+q*4+{0..3} (consecutive)
// -> pack4fp8 + one dword store per N-tile. No LDS. X read exactly once.
// Frag layout assumption (canonical gfx950): lane l = (l&15) + 16*kg holds 8
// contiguous k elements [kg*8 .. kg*8+7] of its row/col.
template <int OUTC, bool INHALF>
__global__ __launch_bounds__(256) void k_gemm_mfma(const void* __restrict__ Xv,
                                                   const _Float16* __restrict__ wT,
                                                   const float* __restrict__ dinv,
                                                   unsigned char* __restrict__ Yb, int n) {
    constexpr int NT = OUTC / 16;  // 8 (128) or 4 (64)
    int tid = threadIdx.x;
    int wave = tid >> 6;
    int lane = tid & 63;
    int tx = lane & 15;
    int q = lane >> 4;
    int r0 = blockIdx.x * 64 + wave * 16;
    int m = r0 + tx;
    int mc = min(m, n - 1);

    f32x4 acc[NT];
#pragma unroll
    for (int nt = 0; nt < NT; nt++) acc[nt] = (f32x4)(0.0f);

#pragma unroll
    for (int ks = 0; ks < 4; ks++) {
        int k0 = ks * 32 + q * 8;
        f16x8 bfrag;
        if constexpr (INHALF) {
            bfrag = *(const f16x8*)((const _Float16*)Xv + (size_t)mc * 128 + k0);
        } else {
            const float* xr = (const float*)Xv + (size_t)mc * 128 + k0;
            float4 x0 = *(const float4*)xr;
            float4 x1 = *(const float4*)(xr + 4);
            bfrag[0] = (_Float16)x0.x; bfrag[1] = (_Float16)x0.y;
            bfrag[2] = (_Float16)x0.z; bfrag[3] = (_Float16)x0.w;
            bfrag[4] = (_Float16)x1.x; bfrag[5] = (_Float16)x1.y;
            bfrag[6] = (_Float16)x1.z; bfrag[7] = (_Float16)x1.w;
        }
#pragma unroll
        for (int nt = 0; nt < NT; nt++) {
            f16x8 afrag = *(const f16x8*)(wT + (size_t)(nt * 16 + tx) * 128 + k0);
            acc[nt] = __builtin_amdgcn_mfma_f32_16x16x32_f16(afrag, bfrag, acc[nt], 0, 0, 0);
        }
    }
    if (m < n) {
        float dv = dinv[m];
        unsigned char* yrow = Yb + (size_t)m * OUTC;
#pragma unroll
        for (int nt = 0; nt < NT; nt++) {
            unsigned d = pack4fp8(acc[nt][0] * dv, acc[nt][1] * dv, acc[nt][2] * dv, acc[nt][3] * dv);
            *(unsigned*)(yrow + nt * 16 + q * 4) = d;
        }
    }
}

// ---------------- aggregation: out = act(dinv[d]*(sum y[s] + y[d]) + b) ----------------
// ONE NODE PER LANE-GROUP + UNROLL-8: LPE=C/16 lanes own one node's row (16B/lane);
// NPW=64/LPE nodes per wave. 8 independent col loads then 8 independent gathers in
// flight; tail = one masked 8-wide iteration.
template <int C, bool OUTHALF>
__global__ __launch_bounds__(256) void k_agg(const uint4* __restrict__ Y4,
                                             const int* __restrict__ rowptr,
                                             const int* __restrict__ col,
                                             const float* __restrict__ dinv,
                                             const float* __restrict__ bias,
                                             void* __restrict__ out, int n, int zidx) {
    constexpr int LPE = C / 16;     // lanes per row: 8 (C=128) or 4 (C=64)
    constexpr int NPW = 64 / LPE;   // nodes per wave: 8 or 16
    constexpr int RS = C / 16;      // uint4 per row
    int gid = blockIdx.x * blockDim.x + threadIdx.x;
    int wid = gid >> 6;
    int lane = gid & 63;
    int g = lane / LPE;
    int sub = lane % LPE;
    int node = wid * NPW + g;
    bool valid = node < n;
    int nc = valid ? node : 0;
    int s0 = rowptr[nc];
    int s1 = valid ? rowptr[nc + 1] : s0;

    float a0[16];
#pragma unroll
    for (int k = 0; k < 16; k++) a0[k] = 0.f;

    {
        int idx = valid ? node : zidx;
        uint4 v = Y4[(size_t)idx * RS + sub];
        acc16(a0, v);
    }
    int e = s0;
    for (; e + 8 <= s1; e += 8) {
        int c0 = col[e];
        int c1 = col[e + 1];
        int c2 = col[e + 2];
        int c3 = col[e + 3];
        int c4 = col[e + 4];
        int c5 = col[e + 5];
        int c6 = col[e + 6];
        int c7 = col[e + 7];
        uint4 v0 = Y4[(size_t)c0 * RS + sub];
        uint4 v1 = Y4[(size_t)c1 * RS + sub];
        uint4 v2 = Y4[(size_t)c2 * RS + sub];
        uint4 v3 = Y4[(size_t)c3 * RS + sub];
        uint4 v4 = Y4[(size_t)c4 * RS + sub];
        uint4 v5 = Y4[(size_t)c5 * RS + sub];
        uint4 v6 = Y4[(size_t)c6 * RS + sub];
        uint4 v7 = Y4[(size_t)c7 * RS + sub];
        acc16(a0, v0);
        acc16(a0, v1);
        acc16(a0, v2);
        acc16(a0, v3);
        acc16(a0, v4);
        acc16(a0, v5);
        acc16(a0, v6);
        acc16(a0, v7);
    }
    if (e < s1) {
        int i0 = min(e + 0, s1 - 1), i1 = min(e + 1, s1 - 1);
        int i2 = min(e + 2, s1 - 1), i3 = min(e + 3, s1 - 1);
        int i4 = min(e + 4, s1 - 1), i5 = min(e + 5, s1 - 1);
        int i6 = min(e + 6, s1 - 1), i7 = min(e + 7, s1 - 1);
        int c0 = (e + 0 < s1) ? col[i0] : zidx;
        int c1 = (e + 1 < s1) ? col[i1] : zidx;
        int c2 = (e + 2 < s1) ? col[i2] : zidx;
        int c3 = (e + 3 < s1) ? col[i3] : zidx;
        int c4 = (e + 4 < s1) ? col[i4] : zidx;
        int c5 = (e + 5 < s1) ? col[i5] : zidx;
        int c6 = (e + 6 < s1) ? col[i6] : zidx;
        int c7 = (e + 7 < s1) ? col[i7] : zidx;
        uint4 v0 = Y4[(size_t)c0 * RS + sub];
        uint4 v1 = Y4[(size_t)c1 * RS + sub];
        uint4 v2 = Y4[(size_t)c2 * RS + sub];
        uint4 v3 = Y4[(size_t)c3 * RS + sub];
        uint4 v4 = Y4[(size_t)c4 * RS + sub];
        uint4 v5 = Y4[(size_t)c5 * RS + sub];
        uint4 v6 = Y4[(size_t)c6 * RS + sub];
        uint4 v7 = Y4[(size_t)c7 * RS + sub];
        acc16(a0, v0);
        acc16(a0, v1);
        acc16(a0, v2);
        acc16(a0, v3);
        acc16(a0, v4);
        acc16(a0, v5);
        acc16(a0, v6);
        acc16(a0, v7);
    }

    if (valid) {
        float dv = dinv[node];
        float4 bv[4];
        bv[0] = *(const float4*)&bias[sub * 16];
        bv[1] = *(const float4*)&bias[sub * 16 + 4];
        bv[2] = *(const float4*)&bias[sub * 16 + 8];
        bv[3] = *(const float4*)&bias[sub * 16 + 12];
        float o[16];
#pragma unroll
        for (int q = 0; q < 4; q++) {
            const float* bq = (const float*)&bv[q];
#pragma unroll
            for (int b = 0; b < 4; b++) o[q * 4 + b] = sigmoidf_(a0[q * 4 + b] * dv + bq[b]);
        }
        if constexpr (OUTHALF) {
            constexpr int OR = C / 8;  // uint4 per f16 row
            uint4 h0, h1;
            h0.x = packh2(o[0], o[1]);   h0.y = packh2(o[2], o[3]);
            h0.z = packh2(o[4], o[5]);   h0.w = packh2(o[6], o[7]);
            h1.x = packh2(o[8], o[9]);   h1.y = packh2(o[10], o[11]);
            h1.z = packh2(o[12], o[13]); h1.w = packh2(o[14], o[15]);
            ((uint4*)out)[(size_t)node * OR + sub * 2] = h0;
            ((uint4*)out)[(size_t)node * OR + sub * 2 + 1] = h1;
        } else {
            float* op = (float*)out + (size_t)node * C + sub * 16;
            *(float4*)(op + 0)  = make_float4(o[0], o[1], o[2], o[3]);
            *(float4*)(op + 4)  = make_float4(o[4], o[5], o[6], o[7]);
            *(float4*)(op + 8)  = make_float4(o[8], o[9], o[10], o[11]);
            *(float4*)(op + 12) = make_float4(o[12], o[13], o[14], o[15]);
        }
    }
}

extern "C" void kernel_launch(void* const* d_in, const int* in_sizes, int n_in,
                              void* d_out, int out_size, void* d_ws, size_t ws_size,
                              hipStream_t stream) {
    const float* x  = (const float*)d_in[0];
    const int* eidx = (const int*)d_in[1];
    const float* W1 = (const float*)d_in[2];
    const float* b1 = (const float*)d_in[3];
    const float* W2 = (const float*)d_in[4];
    const float* b2 = (const float*)d_in[5];
    float* out = (float*)d_out;

    int n = in_sizes[0] / IN_CH;
    int E = in_sizes[1] / 2;
    const int* srcv = eidx;
    const int* dstv = eidx + E;
    int NB = (n + NODES_PER_BUCKET - 1) / NODES_PER_BUCKET;  // 782 (must be <=1024)

    char* w = (char*)d_ws;
    auto alloc = [&](size_t bytes) {
        char* p = w;
        w += (bytes + 255) & ~(size_t)255;
        return p;
    };
    int* bucketCnt      = (int*)alloc((size_t)NB * 4);
    int* bucketBase     = (int*)alloc((size_t)NB * 4);
    unsigned* pairBuf   = (unsigned*)alloc((size_t)NB * BUCKET_CAP * 4);
    int* rowptr         = (int*)alloc(((size_t)n + 1) * 4);
    float* dinv         = (float*)alloc((size_t)n * 4);
    int* col            = (int*)alloc((size_t)E * 4);
    unsigned char* y    = (unsigned char*)alloc(((size_t)n + 1) * 128);  // fp8 [n+1][128B]; reused for y2 [n][64B]
    unsigned short* h   = (unsigned short*)alloc((size_t)n * IN_CH * 2); // f16 [n][128]
    _Float16* wT1       = (_Float16*)alloc(128 * 128 * 2);               // f16 [128][128] (W1^T)
    _Float16* wT2       = (_Float16*)alloc(64 * 128 * 2);                // f16 [64][128]  (W2^T)

    hipMemsetAsync(bucketCnt, 0, (size_t)NB * 4, stream);
    // zero row: serves agg1 (row n, 128B rows) and agg2 (row 2n, 64B rows — same bytes)
    hipMemsetAsync(y + (size_t)n * 128, 0, 128, stream);

    k_wprep<<<64, 256, 0, stream>>>(W1, W2, wT1, wT2);
    int nblk = (E + EPB - 1) / EPB;  // 391
    k_bucket_scatter<<<nblk, 256, 0, stream>>>(srcv, dstv, E, bucketCnt, NB, pairBuf);
    k_scan_buckets<<<1, 1024, 0, stream>>>(bucketCnt, NB, bucketBase, rowptr, n);
    k_bucket_place2<<<NB, 256, 0, stream>>>(pairBuf, bucketCnt, bucketBase, rowptr, dinv, col, n);

    int gemmGrid = (n + 63) / 64;

    // layer 1 (MFMA GEMM, no LDS; 8 nodes/wave agg)
    k_gemm_mfma<128, false><<<gemmGrid, 256, 0, stream>>>(x, wT1, dinv, y, n);
    k_agg<128, true><<<(n + 31) / 32, 256, 0, stream>>>((const uint4*)y, rowptr, col, dinv, b1, h, n, n);
    // layer 2 (y reused as fp8 [n][64B], zero row at 2n)
    k_gemm_mfma<64, true><<<gemmGrid, 256, 0, stream>>>(h, wT2, dinv, y, n);
    k_agg<64, false><<<(n + 63) / 64, 256, 0, stream>>>((const uint4*)y, rowptr, col, dinv, b2, out, n, 2 * n);
}